// Round 5
// baseline (809.095 us; speedup 1.0000x reference)
//
#include <hip/hip_runtime.h>

// VGAE: 8 GCN layers, N=100000, E=1.6M, dims 64/128 — bf16 + MFMA, fused layers.
// GCN(x,W,b) = P(x)@W + b, P(y) = Adjn@y + dinv^2*y (linear, commutes with W).
// K1: h = relu(P(x)@w_in+b).  K2: gather P(h) once -> chain mu1->tmu, si1->tsi -> T=[tmu|tsi].
// K34: one 128-prop of T -> mu(relu), si(sigmoid), z=mu+si*eps.  K5: pz=P(z).
// K6: r2 = relu(P(pz)@(w_z@w_d0) + cvec*(b_z@w_d0) + b_d0).  K7: logits = P(r2)@w_out+b.

typedef short bf16x8 __attribute__((ext_vector_type(8)));
typedef float f32x4 __attribute__((ext_vector_type(4)));

__device__ __forceinline__ ushort f2bf(float f) {           // RNE
    uint x = __float_as_uint(f);
    uint r = x + 0x7FFFu + ((x >> 16) & 1u);
    return (ushort)(r >> 16);
}
__device__ __forceinline__ float bf2f(ushort h) {
    return __uint_as_float(((uint)h) << 16);
}

// ------------------------------------------------------------------ counts: deg + binned histogram
__global__ __launch_bounds__(1024) void counts_kernel(const int* __restrict__ dst,
        int* __restrict__ deg, int* __restrict__ bc0, int E, int NB, int shift) {
    __shared__ int h[8192];
    for (int j = threadIdx.x; j < NB; j += 1024) h[j] = 0;
    __syncthreads();
    int stride = gridDim.x * 1024;
    for (int i = blockIdx.x * 1024 + threadIdx.x; i < E; i += stride) {
        int d = dst[i];
        atomicAdd(&deg[d], 1);
        atomicAdd(&h[d >> shift], 1);
    }
    __syncthreads();
    for (int j = threadIdx.x; j < NB; j += 1024) {
        int v = h[j];
        if (v) atomicAdd(&bc0[j], v);
    }
}

__global__ void dinv_kernel(const int* __restrict__ deg, float* __restrict__ dinv, int N) {
    int i = blockIdx.x * blockDim.x + threadIdx.x;
    if (i < N) dinv[i] = rsqrtf((float)(deg[i] + 1));
}

// ------------------------------------------------------------------ scan
__global__ __launch_bounds__(1024) void scan_block_kernel(const int* __restrict__ in,
                                                          int* __restrict__ out,
                                                          int* __restrict__ bsum, int n) {
    __shared__ int s[1024];
    int i = blockIdx.x * 1024 + threadIdx.x;
    int v = (i < n) ? in[i] : 0;
    s[threadIdx.x] = v;
    __syncthreads();
    for (int off = 1; off < 1024; off <<= 1) {
        int t = (threadIdx.x >= off) ? s[threadIdx.x - off] : 0;
        __syncthreads();
        s[threadIdx.x] += t;
        __syncthreads();
    }
    if (i < n) out[i] = s[threadIdx.x] - v;
    if (threadIdx.x == 1023) bsum[blockIdx.x] = s[1023];
}

__global__ __launch_bounds__(1024) void scan_partials_kernel(int* __restrict__ bsum, int nb) {
    __shared__ int s[1024];
    int v = (threadIdx.x < nb) ? bsum[threadIdx.x] : 0;
    s[threadIdx.x] = v;
    __syncthreads();
    for (int off = 1; off < 1024; off <<= 1) {
        int t = (threadIdx.x >= off) ? s[threadIdx.x - off] : 0;
        __syncthreads();
        s[threadIdx.x] += t;
        __syncthreads();
    }
    if (threadIdx.x < nb) bsum[threadIdx.x] = s[threadIdx.x] - v;
}

__global__ __launch_bounds__(1024) void scan_add_kernel(int* __restrict__ arr,
                                                        const int* __restrict__ bsum, int n, int total) {
    int i = blockIdx.x * 1024 + threadIdx.x;
    if (i < n) arr[i] += bsum[blockIdx.x];
    if (i == 0) arr[n] = total;
}

// ------------------------------------------------------------------ bin scatter + place
__global__ void scatter_kernel(const int* __restrict__ src, const int* __restrict__ dst,
                               const int* __restrict__ bin_start, int* __restrict__ bc1,
                               int2* __restrict__ ebuf, int E, int shift) {
    int i = blockIdx.x * blockDim.x + threadIdx.x;
    if (i < E) {
        int d = dst[i];
        int b = d >> shift;
        int pos = bin_start[b] + atomicAdd(&bc1[b], 1);
        ebuf[pos] = make_int2(src[i], d);
    }
}

__global__ void place2_kernel(const int2* __restrict__ ebuf, const int* __restrict__ row_start,
                              int* __restrict__ cnt, int2* __restrict__ csr,
                              const float* __restrict__ dinv, int E) {
    int i = blockIdx.x * blockDim.x + threadIdx.x;
    if (i < E) {
        int2 e = ebuf[i];
        int pos = row_start[e.y] + atomicAdd(&cnt[e.y], 1);
        csr[pos] = make_int2(e.x, __float_as_int(dinv[e.x] * dinv[e.y]));
    }
}

// ------------------------------------------------------------------ cvec[j] = dinv_j^2 + sum_w
__global__ void rowsum_kernel(const int2* __restrict__ csr, const int* __restrict__ row_start,
                              const float* __restrict__ dinv, float* __restrict__ cvec, int N) {
    int j = blockIdx.x * blockDim.x + threadIdx.x;
    if (j >= N) return;
    float s = dinv[j] * dinv[j];
    int b = row_start[j], e = row_start[j + 1];
    for (int k = b; k < e; ++k) s += __int_as_float(csr[k].y);
    cvec[j] = s;
}

// ------------------------------------------------------------------ Wc = w_z@w_d0 packed bf16, bzw = b_z@w_d0
__global__ void wcpack_kernel(const float* __restrict__ w_z, const float* __restrict__ b_z,
                              const float* __restrict__ w_d0,
                              ushort* __restrict__ P_wc, float* __restrict__ bzw) {
    int o = blockIdx.x * 256 + threadIdx.x;
    if (o >= 65 * 128) return;
    int i = o >> 7, j = o & 127;
    float s = 0.f;
    for (int k = 0; k < 128; ++k) {
        float a = (i < 64) ? w_z[i * 128 + k] : b_z[k];
        s = fmaf(a, w_d0[k * 128 + j], s);
    }
    if (i < 64) {
        int c = j >> 4, kb = i >> 5, l = ((i >> 3) & 3) * 16 + (j & 15), e = i & 7;
        P_wc[(size_t)((c * 2 + kb) * 64 + l) * 8 + e] = f2bf(s);
    } else bzw[j] = s;
}

// ------------------------------------------------------------------ weight packs (6 weights, 1 launch)
// Wp[((c*KB+kb)*64+l)*8+e] = bf16(W[kb*32+(l>>4)*8+e][c*16+(l&15)])
__device__ __forceinline__ void pack_one(const float* __restrict__ W, ushort* __restrict__ P,
                                         int KI, int KO, int idx) {
    if (idx >= KI * KO) return;
    int e = idx & 7, l = (idx >> 3) & 63, t = idx >> 9;
    int KB = KI / 32;
    int c = t / KB, kb = t % KB;
    int k = kb * 32 + ((l >> 4) << 3) + e, col = c * 16 + (l & 15);
    P[idx] = f2bf(W[(size_t)k * KO + col]);
}

__global__ void megapack_kernel(const float* w_in, const float* w_mu0, const float* w_si0,
                                const float* w_mu, const float* w_si, const float* w_out,
                                ushort* P_in, ushort* P_mu0, ushort* P_si0,
                                ushort* P_mu, ushort* P_si, ushort* P_out) {
    int b = blockIdx.x, tid = threadIdx.x;
    if (b < 32)       pack_one(w_in,  P_in,  64, 128,  (b - 0)   * 256 + tid);
    else if (b < 96)  pack_one(w_mu0, P_mu0, 128, 128, (b - 32)  * 256 + tid);
    else if (b < 160) pack_one(w_si0, P_si0, 128, 128, (b - 96)  * 256 + tid);
    else if (b < 192) pack_one(w_mu,  P_mu,  128, 64,  (b - 160) * 256 + tid);
    else if (b < 224) pack_one(w_si,  P_si,  128, 64,  (b - 192) * 256 + tid);
    else              pack_one(w_out, P_out, 128, 128, (b - 224) * 256 + tid);
}

// ------------------------------------------------------------------ f32 -> bf16
__global__ void cvt8_kernel(const float* __restrict__ in, ushort* __restrict__ out, int n8) {
    int i = blockIdx.x * 256 + threadIdx.x;
    if (i >= n8) return;
    float4 a = ((const float4*)in)[i * 2];
    float4 b = ((const float4*)in)[i * 2 + 1];
    bf16x8 o;
    o[0] = (short)f2bf(a.x); o[1] = (short)f2bf(a.y);
    o[2] = (short)f2bf(a.z); o[3] = (short)f2bf(a.w);
    o[4] = (short)f2bf(b.x); o[5] = (short)f2bf(b.y);
    o[6] = (short)f2bf(b.z); o[7] = (short)f2bf(b.w);
    ((bf16x8*)out)[i] = o;
}

// ================================================================== fused building blocks
// LDS stages are bf16 row-major with padded stride (WI*2+16 bytes) -> 2-way max conflicts.

template <int WI>
__device__ __forceinline__ void gather_phase(char* Ls, const ushort* __restrict__ xb,
        const int* __restrict__ row_start, const int2* __restrict__ csr,
        const float* __restrict__ dinv, int rowbase, int N, int tid) {
    constexpr int L = WI / 8, EPL = 64 / L;
    constexpr int STR = WI * 2 + 16;
    int w = tid >> 6, lane = tid & 63;
    int sub = lane / L, f8 = lane % L;
    #pragma unroll 1
    for (int i = 0; i < 16; ++i) {
        int lrow = w * 16 + i;
        int node = rowbase + lrow;
        float acc[8] = {0.f, 0.f, 0.f, 0.f, 0.f, 0.f, 0.f, 0.f};
        if (node < N) {
            int beg = row_start[node], end = row_start[node + 1];
            float d2 = dinv[node]; d2 *= d2;
            float a0[8] = {}, a1[8] = {};
            for (int base = beg; base < end; base += 2 * EPL) {
                int e0 = base + sub, e1 = base + EPL + sub;
                int2 p0 = csr[e0 < end ? e0 : 0];
                int2 p1 = csr[e1 < end ? e1 : 0];
                float w0 = (e0 < end) ? __int_as_float(p0.y) : 0.f;
                float w1 = (e1 < end) ? __int_as_float(p1.y) : 0.f;
                bf16x8 v0 = *(const bf16x8*)(xb + (size_t)p0.x * WI + f8 * 8);
                bf16x8 v1 = *(const bf16x8*)(xb + (size_t)p1.x * WI + f8 * 8);
                #pragma unroll
                for (int q = 0; q < 8; ++q) a0[q] = fmaf(w0, bf2f((ushort)v0[q]), a0[q]);
                #pragma unroll
                for (int q = 0; q < 8; ++q) a1[q] = fmaf(w1, bf2f((ushort)v1[q]), a1[q]);
            }
            #pragma unroll
            for (int q = 0; q < 8; ++q) acc[q] = a0[q] + a1[q];
            #pragma unroll
            for (int m = L; m < 64; m <<= 1) {
                #pragma unroll
                for (int q = 0; q < 8; ++q) acc[q] += __shfl_xor(acc[q], m);
            }
            bf16x8 sv = *(const bf16x8*)(xb + (size_t)node * WI + f8 * 8);
            #pragma unroll
            for (int q = 0; q < 8; ++q) acc[q] = fmaf(d2, bf2f((ushort)sv[q]), acc[q]);
        }
        if (sub == 0) {
            bf16x8 o;
            #pragma unroll
            for (int q = 0; q < 8; ++q) o[q] = (short)f2bf(acc[q]);
            *(bf16x8*)(Ls + lrow * STR + f8 * 16) = o;
        }
    }
}

// A: row = w*16+(l&15), k-chunk kb: cols kb*32+(l>>4)*8..+8. C: col=c*16+(l&15), row=w*16+(l>>4)*4+r.
template <int KI, int KO>
__device__ __forceinline__ void mfma_phase(const char* Ls, const bf16x8* __restrict__ Wp,
                                           float (*acc)[4], int tid) {
    constexpr int KB = KI / 32, CT = KO / 16, STR = KI * 2 + 16;
    int w = tid >> 6, l = tid & 63;
    int row = w * 16 + (l & 15);
    int lk = l >> 4;
    bf16x8 a[KB];
    #pragma unroll
    for (int kb = 0; kb < KB; ++kb)
        a[kb] = *(const bf16x8*)(Ls + row * STR + kb * 64 + lk * 16);
    #pragma unroll
    for (int c = 0; c < CT; ++c) {
        f32x4 v = {0.f, 0.f, 0.f, 0.f};
        #pragma unroll
        for (int kb = 0; kb < KB; ++kb)
            v = __builtin_amdgcn_mfma_f32_16x16x32_bf16(a[kb], Wp[((size_t)c * KB + kb) * 64 + l], v, 0, 0, 0);
        acc[c][0] = v[0]; acc[c][1] = v[1]; acc[c][2] = v[2]; acc[c][3] = v[3];
    }
}

template <int DW>
__device__ __forceinline__ void cstore_bf16(char* Ls, const float* v, int cbase, int tid) {
    constexpr int STR = DW * 2 + 16;
    int w = tid >> 6, l = tid & 63;
    int col = cbase + (l & 15);
    int row0 = w * 16 + (l >> 4) * 4;
    #pragma unroll
    for (int r = 0; r < 4; ++r)
        *(ushort*)(Ls + (row0 + r) * STR + col * 2) = f2bf(v[r]);
}

template <int KO>
__device__ __forceinline__ void flush_bf16(const char* Ls, ushort* __restrict__ out,
                                           int rowbase, int N, int tid) {
    constexpr int STR = KO * 2 + 16, CH = 64 * KO / 8;
    for (int idx = tid; idx < CH; idx += 256) {
        int row = idx / (KO / 8), sl = idx % (KO / 8);
        if (rowbase + row < N) {
            bf16x8 vv = *(const bf16x8*)(Ls + row * STR + sl * 16);
            *(bf16x8*)(out + (size_t)(rowbase + row) * KO + sl * 8) = vv;
        }
    }
}

// ------------------------------------------------------------------ K1: h = relu(P(x)@w_in + b)   (WI=64 -> KO=128 bf16)
__global__ __launch_bounds__(256) void fused_h_kernel(const ushort* __restrict__ xb,
        const int* __restrict__ row_start, const int2* __restrict__ csr,
        const float* __restrict__ dinv, const bf16x8* __restrict__ Wp,
        const float* __restrict__ bias, ushort* __restrict__ out, int N) {
    __shared__ __align__(16) char Ls[64 * (128 * 2 + 16)];
    int tid = threadIdx.x;
    int rowbase = blockIdx.x * 64;
    gather_phase<64>(Ls, xb, row_start, csr, dinv, rowbase, N, tid);
    __syncthreads();
    float acc[8][4];
    mfma_phase<64, 128>(Ls, Wp, acc, tid);
    __syncthreads();
    int l = tid & 63;
    #pragma unroll
    for (int c = 0; c < 8; ++c) {
        float bv = bias[c * 16 + (l & 15)];
        float v[4];
        #pragma unroll
        for (int r = 0; r < 4; ++r) v[r] = fmaxf(acc[c][r] + bv, 0.f);
        cstore_bf16<128>(Ls, v, c * 16, tid);
    }
    __syncthreads();
    flush_bf16<128>(Ls, out, rowbase, N, tid);
}

// ------------------------------------------------------------------ K2: gather P(h), chain 4 gemms -> T=[tmu|tsi]
__global__ __launch_bounds__(256) void fused_enc_kernel(const ushort* __restrict__ hb,
        const int* __restrict__ row_start, const int2* __restrict__ csr,
        const float* __restrict__ dinv,
        const bf16x8* __restrict__ P_mu0, const float* __restrict__ b_mu0,
        const bf16x8* __restrict__ P_mu,
        const bf16x8* __restrict__ P_si0, const float* __restrict__ b_si0,
        const bf16x8* __restrict__ P_si,
        ushort* __restrict__ T, int N) {
    constexpr int SEG = 64 * (128 * 2 + 16);
    __shared__ __align__(16) char Ls[2 * SEG];
    char* L0 = Ls;
    char* L1 = Ls + SEG;
    int tid = threadIdx.x;
    int rowbase = blockIdx.x * 64;
    int l = tid & 63;

    gather_phase<128>(L0, hb, row_start, csr, dinv, rowbase, N, tid);
    __syncthreads();

    float acc[8][4];
    // mu1 = relu(ph@w_mu0 + b)
    mfma_phase<128, 128>(L0, P_mu0, acc, tid);
    #pragma unroll
    for (int c = 0; c < 8; ++c) {
        float bv = b_mu0[c * 16 + (l & 15)];
        float v[4];
        #pragma unroll
        for (int r = 0; r < 4; ++r) v[r] = fmaxf(acc[c][r] + bv, 0.f);
        cstore_bf16<128>(L1, v, c * 16, tid);
    }
    __syncthreads();
    // tmu = mu1@w_mu
    float rmu[4][4];
    mfma_phase<128, 64>(L1, P_mu, rmu, tid);
    __syncthreads();
    // si1 = relu(ph@w_si0 + b)
    mfma_phase<128, 128>(L0, P_si0, acc, tid);
    #pragma unroll
    for (int c = 0; c < 8; ++c) {
        float bv = b_si0[c * 16 + (l & 15)];
        float v[4];
        #pragma unroll
        for (int r = 0; r < 4; ++r) v[r] = fmaxf(acc[c][r] + bv, 0.f);
        cstore_bf16<128>(L1, v, c * 16, tid);
    }
    __syncthreads();
    // tsi = si1@w_si
    float rsi[4][4];
    mfma_phase<128, 64>(L1, P_si, rsi, tid);
    __syncthreads();
    // T-stage: tmu -> cols 0..63, tsi -> cols 64..127
    #pragma unroll
    for (int c = 0; c < 4; ++c) {
        cstore_bf16<128>(L0, rmu[c], c * 16, tid);
        cstore_bf16<128>(L0, rsi[c], 64 + c * 16, tid);
    }
    __syncthreads();
    flush_bf16<128>(L0, T, rowbase, N, tid);
}

// ------------------------------------------------------------------ K34: one 128-prop of T -> mu, si, z
__global__ __launch_bounds__(256) void mssz_kernel(const ushort* __restrict__ T,
        const int* __restrict__ row_start, const int2* __restrict__ csr,
        const float* __restrict__ dinv, const float* __restrict__ b_mu,
        const float* __restrict__ b_si, const float* __restrict__ eps,
        float* __restrict__ M, float* __restrict__ S, ushort* __restrict__ zb, int N) {
    constexpr int L = 16, EPL = 4;
    int wave = threadIdx.x >> 6, lane = threadIdx.x & 63;
    int node = blockIdx.x * 4 + wave;
    if (node >= N) return;
    int sub = lane / L, f8 = lane % L;
    int beg = row_start[node], end = row_start[node + 1];
    float d2 = dinv[node]; d2 *= d2;
    float a0[8] = {}, a1[8] = {};
    for (int base = beg; base < end; base += 2 * EPL) {
        int e0 = base + sub, e1 = base + EPL + sub;
        int2 p0 = csr[e0 < end ? e0 : 0];
        int2 p1 = csr[e1 < end ? e1 : 0];
        float w0 = (e0 < end) ? __int_as_float(p0.y) : 0.f;
        float w1 = (e1 < end) ? __int_as_float(p1.y) : 0.f;
        bf16x8 v0 = *(const bf16x8*)(T + (size_t)p0.x * 128 + f8 * 8);
        bf16x8 v1 = *(const bf16x8*)(T + (size_t)p1.x * 128 + f8 * 8);
        #pragma unroll
        for (int q = 0; q < 8; ++q) a0[q] = fmaf(w0, bf2f((ushort)v0[q]), a0[q]);
        #pragma unroll
        for (int q = 0; q < 8; ++q) a1[q] = fmaf(w1, bf2f((ushort)v1[q]), a1[q]);
    }
    float acc[8];
    #pragma unroll
    for (int q = 0; q < 8; ++q) acc[q] = a0[q] + a1[q];
    #pragma unroll
    for (int m = 16; m < 64; m <<= 1) {
        #pragma unroll
        for (int q = 0; q < 8; ++q) acc[q] += __shfl_xor(acc[q], m);
    }
    if (sub != 0) return;
    bf16x8 sv = *(const bf16x8*)(T + (size_t)node * 128 + f8 * 8);
    #pragma unroll
    for (int q = 0; q < 8; ++q) acc[q] = fmaf(d2, bf2f((ushort)sv[q]), acc[q]);

    bool is_mu = (f8 < 8);
    const float* bp = is_mu ? b_mu : b_si;
    int o = (f8 & 7) * 8;
    float val[8];
    #pragma unroll
    for (int q = 0; q < 8; ++q) {
        float t = acc[q] + bp[o + q];
        val[q] = is_mu ? fmaxf(t, 0.f) : 1.f / (1.f + __expf(-t));
    }
    if (is_mu) {
        *(float4*)&M[(size_t)node * 64 + o]     = make_float4(val[0], val[1], val[2], val[3]);
        *(float4*)&M[(size_t)node * 64 + o + 4] = make_float4(val[4], val[5], val[6], val[7]);
    } else {
        *(float4*)&S[(size_t)node * 64 + o]     = make_float4(val[0], val[1], val[2], val[3]);
        *(float4*)&S[(size_t)node * 64 + o + 4] = make_float4(val[4], val[5], val[6], val[7]);
    }
    float oth[8];
    #pragma unroll
    for (int q = 0; q < 8; ++q) oth[q] = __shfl_xor(val[q], 8);
    if (is_mu) {
        float4 e0v = *(const float4*)&eps[(size_t)node * 64 + o];
        float4 e1v = *(const float4*)&eps[(size_t)node * 64 + o + 4];
        float ev[8] = {e0v.x, e0v.y, e0v.z, e0v.w, e1v.x, e1v.y, e1v.z, e1v.w};
        bf16x8 z;
        #pragma unroll
        for (int q = 0; q < 8; ++q) z[q] = (short)f2bf(fmaf(oth[q], ev[q], val[q]));
        *(bf16x8*)(zb + (size_t)node * 64 + o) = z;
    }
}

// ------------------------------------------------------------------ K5: plain 64-wide bf16 prop (pz = P(z))
__global__ __launch_bounds__(256) void prop64_kernel(const ushort* __restrict__ xb,
        ushort* __restrict__ out, const int* __restrict__ row_start,
        const int2* __restrict__ csr, const float* __restrict__ dinv, int N) {
    constexpr int L = 8, EPL = 8;
    int wave = threadIdx.x >> 6, lane = threadIdx.x & 63;
    int node = blockIdx.x * 4 + wave;
    if (node >= N) return;
    int sub = lane / L, f8 = lane % L;
    int beg = row_start[node], end = row_start[node + 1];
    float d2 = dinv[node]; d2 *= d2;
    float a0[8] = {}, a1[8] = {};
    for (int base = beg; base < end; base += 2 * EPL) {
        int e0 = base + sub, e1 = base + EPL + sub;
        int2 p0 = csr[e0 < end ? e0 : 0];
        int2 p1 = csr[e1 < end ? e1 : 0];
        float w0 = (e0 < end) ? __int_as_float(p0.y) : 0.f;
        float w1 = (e1 < end) ? __int_as_float(p1.y) : 0.f;
        bf16x8 v0 = *(const bf16x8*)(xb + (size_t)p0.x * 64 + f8 * 8);
        bf16x8 v1 = *(const bf16x8*)(xb + (size_t)p1.x * 64 + f8 * 8);
        #pragma unroll
        for (int q = 0; q < 8; ++q) a0[q] = fmaf(w0, bf2f((ushort)v0[q]), a0[q]);
        #pragma unroll
        for (int q = 0; q < 8; ++q) a1[q] = fmaf(w1, bf2f((ushort)v1[q]), a1[q]);
    }
    float acc[8];
    #pragma unroll
    for (int q = 0; q < 8; ++q) acc[q] = a0[q] + a1[q];
    #pragma unroll
    for (int m = 8; m < 64; m <<= 1) {
        #pragma unroll
        for (int q = 0; q < 8; ++q) acc[q] += __shfl_xor(acc[q], m);
    }
    if (sub != 0) return;
    bf16x8 sv = *(const bf16x8*)(xb + (size_t)node * 64 + f8 * 8);
    bf16x8 oz;
    #pragma unroll
    for (int q = 0; q < 8; ++q) oz[q] = (short)f2bf(fmaf(d2, bf2f((ushort)sv[q]), acc[q]));
    *(bf16x8*)(out + (size_t)node * 64 + f8 * 8) = oz;
}

// ------------------------------------------------------------------ K6: r2 = relu(P(pz)@Wc + cvec*bzw + b_d0)
__global__ __launch_bounds__(256) void fused_r2_kernel(const ushort* __restrict__ pzb,
        const int* __restrict__ row_start, const int2* __restrict__ csr,
        const float* __restrict__ dinv, const bf16x8* __restrict__ Wp,
        const float* __restrict__ bzw, const float* __restrict__ b_d0,
        const float* __restrict__ cvec, ushort* __restrict__ out, int N) {
    __shared__ __align__(16) char Ls[64 * (128 * 2 + 16)];
    int tid = threadIdx.x;
    int rowbase = blockIdx.x * 64;
    gather_phase<64>(Ls, pzb, row_start, csr, dinv, rowbase, N, tid);
    __syncthreads();
    float acc[8][4];
    mfma_phase<64, 128>(Ls, Wp, acc, tid);
    __syncthreads();
    int l = tid & 63;
    int w = tid >> 6;
    int row0 = rowbase + w * 16 + (l >> 4) * 4;
    float cvr[4];
    #pragma unroll
    for (int r = 0; r < 4; ++r) {
        int rr = row0 + r;
        cvr[r] = cvec[rr < N ? rr : 0];
    }
    #pragma unroll
    for (int c = 0; c < 8; ++c) {
        int col = c * 16 + (l & 15);
        float bz = bzw[col], bd = b_d0[col];
        float v[4];
        #pragma unroll
        for (int r = 0; r < 4; ++r) v[r] = fmaxf(fmaf(cvr[r], bz, acc[c][r]) + bd, 0.f);
        cstore_bf16<128>(Ls, v, c * 16, tid);
    }
    __syncthreads();
    flush_bf16<128>(Ls, out, rowbase, N, tid);
}

// ------------------------------------------------------------------ K7: logits = P(r2)@w_out + b_out (f32 out)
__global__ __launch_bounds__(256) void fused_out_kernel(const ushort* __restrict__ r2b,
        const int* __restrict__ row_start, const int2* __restrict__ csr,
        const float* __restrict__ dinv, const bf16x8* __restrict__ Wp,
        const float* __restrict__ bias, float* __restrict__ out, int N) {
    __shared__ __align__(16) char Ls[64 * (128 * 4 + 16)];   // 33792: gather stage (17408) then f32 out stage
    int tid = threadIdx.x;
    int rowbase = blockIdx.x * 64;
    gather_phase<128>(Ls, r2b, row_start, csr, dinv, rowbase, N, tid);
    __syncthreads();
    float acc[8][4];
    mfma_phase<128, 128>(Ls, Wp, acc, tid);
    __syncthreads();
    int l = tid & 63;
    int w = tid >> 6;
    constexpr int OSTR = 128 * 4 + 16;
    int row0 = w * 16 + (l >> 4) * 4;
    #pragma unroll
    for (int c = 0; c < 8; ++c) {
        int col = c * 16 + (l & 15);
        float bv = bias[col];
        #pragma unroll
        for (int r = 0; r < 4; ++r)
            *(float*)(Ls + (row0 + r) * OSTR + col * 4) = acc[c][r] + bv;
    }
    __syncthreads();
    for (int idx = tid; idx < 64 * 32; idx += 256) {
        int row = idx >> 5, sl = idx & 31;
        if (rowbase + row < N) {
            f32x4 v = *(const f32x4*)(Ls + row * OSTR + sl * 16);
            *(f32x4*)(out + (size_t)(rowbase + row) * 128 + sl * 4) = v;
        }
    }
}

// ------------------------------------------------------------------ launch
extern "C" void kernel_launch(void* const* d_in, const int* in_sizes, int n_in,
                              void* d_out, int out_size, void* d_ws, size_t ws_size,
                              hipStream_t stream) {
    const float* x    = (const float*)d_in[0];
    const float* eps  = (const float*)d_in[1];
    const int*   ei   = (const int*)d_in[2];
    const float* w_in  = (const float*)d_in[3];  const float* b_in  = (const float*)d_in[4];
    const float* w_mu0 = (const float*)d_in[5];  const float* b_mu0 = (const float*)d_in[6];
    const float* w_mu  = (const float*)d_in[7];  const float* b_mu  = (const float*)d_in[8];
    const float* w_si0 = (const float*)d_in[9];  const float* b_si0 = (const float*)d_in[10];
    const float* w_si  = (const float*)d_in[11]; const float* b_si  = (const float*)d_in[12];
    const float* w_z   = (const float*)d_in[13]; const float* b_z   = (const float*)d_in[14];
    const float* w_d0  = (const float*)d_in[15]; const float* b_d0  = (const float*)d_in[16];
    const float* w_out = (const float*)d_in[17]; const float* b_out = (const float*)d_in[18];

    const int N = in_sizes[0] / 64;
    const int E = in_sizes[2] / 2;
    const int* srcI = ei;
    const int* dstI = ei + E;

    int shift = 4;
    while (((N >> shift) + 1) > 8192) shift++;
    const int NB = (N >> shift) + 1;

    auto align = [](size_t v) { return (v + 255) & ~(size_t)255; };
    char* wsp = (char*)d_ws;
    size_t off = 0;
    int*    deg       = (int*)(wsp + off);    size_t deg_off = off; off = align(off + (size_t)N * 4);
    int*    bc0       = (int*)(wsp + off);    off = align(off + (size_t)NB * 4);
    int*    bc1       = (int*)(wsp + off);    off = align(off + (size_t)NB * 4);
    size_t  zero_span = off - deg_off;
    float*  cvec      = (float*)(wsp + off);  off = align(off + (size_t)N * 4);
    int*    row_start = (int*)(wsp + off);    off = align(off + (size_t)(N + 1) * 4);
    int*    bin_start = (int*)(wsp + off);    off = align(off + (size_t)(NB + 1) * 4);
    int*    bsum      = (int*)(wsp + off);    off = align(off + 1024 * 4);
    float*  dinv      = (float*)(wsp + off);  off = align(off + (size_t)N * 4);
    float*  bzw       = (float*)(wsp + off);  off = align(off + 128 * 4);
    ushort* P_in      = (ushort*)(wsp + off); off = align(off + 64 * 128 * 2);
    ushort* P_mu0     = (ushort*)(wsp + off); off = align(off + 128 * 128 * 2);
    ushort* P_si0     = (ushort*)(wsp + off); off = align(off + 128 * 128 * 2);
    ushort* P_mu      = (ushort*)(wsp + off); off = align(off + 128 * 64 * 2);
    ushort* P_si      = (ushort*)(wsp + off); off = align(off + 128 * 64 * 2);
    ushort* P_wc      = (ushort*)(wsp + off); off = align(off + 64 * 128 * 2);
    ushort* P_out     = (ushort*)(wsp + off); off = align(off + 128 * 128 * 2);
    int2*   csr       = (int2*)(wsp + off);   off = align(off + (size_t)E * 8);
    int2*   ebuf      = (int2*)(wsp + off);   off = align(off + (size_t)E * 8);   // aliased: xb/pz after place2
    ushort* xb        = (ushort*)ebuf;        // [N,64] bf16 (x), later pz
    ushort* B1        = (ushort*)(wsp + off); off = align(off + (size_t)N * 128 * 2);  // h, then z, then r2

    float* Cc = (float*)d_out;               // logits f32 [N,128] (final)
    float* M  = Cc + (size_t)N * 128;        // mu f32 (final)
    float* S  = M + (size_t)N * 64;          // si f32 (final)
    ushort* T  = (ushort*)Cc;                // [tmu|tsi] bf16 [N,128] scratch in Cc
    ushort* zb = B1;                         // z bf16 [N,64] (h dead after K2)
    ushort* pzb = xb;                        // pz bf16 [N,64] (x dead after K1)
    ushort* r2b = B1;                        // r2 bf16 [N,128] (z dead after K5)

    const int TB = 256;
    hipMemsetAsync(deg, 0, zero_span, stream);
    counts_kernel<<<256, 1024, 0, stream>>>(dstI, deg, bc0, E, NB, shift);
    dinv_kernel<<<(N + TB - 1) / TB, TB, 0, stream>>>(deg, dinv, N);
    int nbN = (N + 1023) / 1024;
    scan_block_kernel<<<nbN, 1024, 0, stream>>>(deg, row_start, bsum, N);
    scan_partials_kernel<<<1, 1024, 0, stream>>>(bsum, nbN);
    scan_add_kernel<<<nbN, 1024, 0, stream>>>(row_start, bsum, N, E);
    int nbB = (NB + 1023) / 1024;
    scan_block_kernel<<<nbB, 1024, 0, stream>>>(bc0, bin_start, bsum, NB);
    scan_partials_kernel<<<1, 1024, 0, stream>>>(bsum, nbB);
    scan_add_kernel<<<nbB, 1024, 0, stream>>>(bin_start, bsum, NB, E);
    hipMemsetAsync(deg, 0, (size_t)N * 4, stream);   // deg reused as place counter
    scatter_kernel<<<(E + TB - 1) / TB, TB, 0, stream>>>(srcI, dstI, bin_start, bc1, ebuf, E, shift);
    place2_kernel<<<(E + TB - 1) / TB, TB, 0, stream>>>(ebuf, row_start, deg, csr, dinv, E);
    rowsum_kernel<<<(N + TB - 1) / TB, TB, 0, stream>>>(csr, row_start, dinv, cvec, N);
    wcpack_kernel<<<(65 * 128 + 255) / 256, 256, 0, stream>>>(w_z, b_z, w_d0, P_wc, bzw);
    megapack_kernel<<<288, 256, 0, stream>>>(w_in, w_mu0, w_si0, w_mu, w_si, w_out,
                                             P_in, P_mu0, P_si0, P_mu, P_si, P_out);
    cvt8_kernel<<<((N * 8) + 255) / 256, 256, 0, stream>>>(x, xb, N * 8);   // after place2 (ebuf alias dead)

    int GB = (N + 63) / 64;
    int PG = (N + 3) / 4;

    // K1: h = relu(P(x)@w_in + b_in) -> B1
    fused_h_kernel<<<GB, 256, 0, stream>>>(xb, row_start, csr, dinv,
                                           (const bf16x8*)P_in, b_in, B1, N);
    // K2: gather P(h) -> {mu1->tmu, si1->tsi} -> T (in Cc)
    fused_enc_kernel<<<GB, 256, 0, stream>>>(B1, row_start, csr, dinv,
                                             (const bf16x8*)P_mu0, b_mu0, (const bf16x8*)P_mu,
                                             (const bf16x8*)P_si0, b_si0, (const bf16x8*)P_si,
                                             T, N);
    // K34: prop T -> mu (M), si (S), z (zb = B1; h dead)
    mssz_kernel<<<PG, 256, 0, stream>>>(T, row_start, csr, dinv, b_mu, b_si, eps, M, S, zb, N);
    // K5: pz = P(z) -> pzb (= xb region; x dead)
    prop64_kernel<<<PG, 256, 0, stream>>>(zb, pzb, row_start, csr, dinv, N);
    // K6: r2 = relu(P(pz)@Wc + cvec*bzw + b_d0) -> r2b (= B1; z dead)
    fused_r2_kernel<<<GB, 256, 0, stream>>>(pzb, row_start, csr, dinv,
                                            (const bf16x8*)P_wc, bzw, b_d0, cvec, r2b, N);
    // K7: logits = P(r2)@w_out + b_out -> Cc f32 (T dead)
    fused_out_kernel<<<GB, 256, 0, stream>>>(r2b, row_start, csr, dinv,
                                             (const bf16x8*)P_out, b_out, Cc, N);
}

// Round 6
// 675.128 us; speedup vs baseline: 1.1984x; 1.1984x over previous
//
#include <hip/hip_runtime.h>

// VGAE: 8 GCN layers, N=100000, E=1.6M, dims 64/128 — bf16 + MFMA.
// GCN(x,W,b) = P(x)@W + b, P(y) = Adjn@y + dinv^2*y (linear, commutes with W).
// Structure: high-occupancy wave-per-node props + separate MFMA GEMMs
// (round-5 LDS-fusion regressed: 18% occupancy). Binned CSR build.
// Decoder 1-2 fused: r2 = relu(PP(z)@(w_z@w_d0) + cvec*(b_z@w_d0) + b_d0).

typedef short bf16x8 __attribute__((ext_vector_type(8)));
typedef float f32x4 __attribute__((ext_vector_type(4)));

__device__ __forceinline__ ushort f2bf(float f) {           // RNE
    uint x = __float_as_uint(f);
    uint r = x + 0x7FFFu + ((x >> 16) & 1u);
    return (ushort)(r >> 16);
}
__device__ __forceinline__ float bf2f(ushort h) {
    return __uint_as_float(((uint)h) << 16);
}

// ------------------------------------------------------------------ counts: deg + binned histogram
__global__ __launch_bounds__(1024) void counts_kernel(const int* __restrict__ dst,
        int* __restrict__ deg, int* __restrict__ bc0, int E, int NB, int shift) {
    __shared__ int h[8192];
    for (int j = threadIdx.x; j < NB; j += 1024) h[j] = 0;
    __syncthreads();
    int stride = gridDim.x * 1024;
    for (int i = blockIdx.x * 1024 + threadIdx.x; i < E; i += stride) {
        int d = dst[i];
        atomicAdd(&deg[d], 1);
        atomicAdd(&h[d >> shift], 1);
    }
    __syncthreads();
    for (int j = threadIdx.x; j < NB; j += 1024) {
        int v = h[j];
        if (v) atomicAdd(&bc0[j], v);
    }
}

__global__ void dinv_kernel(const int* __restrict__ deg, float* __restrict__ dinv, int N) {
    int i = blockIdx.x * blockDim.x + threadIdx.x;
    if (i < N) dinv[i] = rsqrtf((float)(deg[i] + 1));
}

// ------------------------------------------------------------------ scan
__global__ __launch_bounds__(1024) void scan_block_kernel(const int* __restrict__ in,
                                                          int* __restrict__ out,
                                                          int* __restrict__ bsum, int n) {
    __shared__ int s[1024];
    int i = blockIdx.x * 1024 + threadIdx.x;
    int v = (i < n) ? in[i] : 0;
    s[threadIdx.x] = v;
    __syncthreads();
    for (int off = 1; off < 1024; off <<= 1) {
        int t = (threadIdx.x >= off) ? s[threadIdx.x - off] : 0;
        __syncthreads();
        s[threadIdx.x] += t;
        __syncthreads();
    }
    if (i < n) out[i] = s[threadIdx.x] - v;
    if (threadIdx.x == 1023) bsum[blockIdx.x] = s[1023];
}

__global__ __launch_bounds__(1024) void scan_partials_kernel(int* __restrict__ bsum, int nb) {
    __shared__ int s[1024];
    int v = (threadIdx.x < nb) ? bsum[threadIdx.x] : 0;
    s[threadIdx.x] = v;
    __syncthreads();
    for (int off = 1; off < 1024; off <<= 1) {
        int t = (threadIdx.x >= off) ? s[threadIdx.x - off] : 0;
        __syncthreads();
        s[threadIdx.x] += t;
        __syncthreads();
    }
    if (threadIdx.x < nb) bsum[threadIdx.x] = s[threadIdx.x] - v;
}

__global__ __launch_bounds__(1024) void scan_add_kernel(int* __restrict__ arr,
                                                        const int* __restrict__ bsum, int n, int total) {
    int i = blockIdx.x * 1024 + threadIdx.x;
    if (i < n) arr[i] += bsum[blockIdx.x];
    if (i == 0) arr[n] = total;
}

// ------------------------------------------------------------------ bin scatter + place
__global__ void scatter_kernel(const int* __restrict__ src, const int* __restrict__ dst,
                               const int* __restrict__ bin_start, int* __restrict__ bc1,
                               int2* __restrict__ ebuf, int E, int shift) {
    int i = blockIdx.x * blockDim.x + threadIdx.x;
    if (i < E) {
        int d = dst[i];
        int b = d >> shift;
        int pos = bin_start[b] + atomicAdd(&bc1[b], 1);
        ebuf[pos] = make_int2(src[i], d);
    }
}

__global__ void place2_kernel(const int2* __restrict__ ebuf, const int* __restrict__ row_start,
                              int* __restrict__ cnt, int2* __restrict__ csr,
                              const float* __restrict__ dinv, int E) {
    int i = blockIdx.x * blockDim.x + threadIdx.x;
    if (i < E) {
        int2 e = ebuf[i];
        int pos = row_start[e.y] + atomicAdd(&cnt[e.y], 1);
        csr[pos] = make_int2(e.x, __float_as_int(dinv[e.x] * dinv[e.y]));
    }
}

// ------------------------------------------------------------------ cvec[j] = dinv_j^2 + sum_w
__global__ void rowsum_kernel(const int2* __restrict__ csr, const int* __restrict__ row_start,
                              const float* __restrict__ dinv, float* __restrict__ cvec, int N) {
    int j = blockIdx.x * blockDim.x + threadIdx.x;
    if (j >= N) return;
    float s = dinv[j] * dinv[j];
    int b = row_start[j], e = row_start[j + 1];
    for (int k = b; k < e; ++k) s += __int_as_float(csr[k].y);
    cvec[j] = s;
}

// ------------------------------------------------------------------ Wc = w_z@w_d0 packed bf16, bzw = b_z@w_d0
__global__ void wcpack_kernel(const float* __restrict__ w_z, const float* __restrict__ b_z,
                              const float* __restrict__ w_d0,
                              ushort* __restrict__ P_wc, float* __restrict__ bzw) {
    int o = blockIdx.x * 256 + threadIdx.x;
    if (o >= 65 * 128) return;
    int i = o >> 7, j = o & 127;
    float s = 0.f;
    for (int k = 0; k < 128; ++k) {
        float a = (i < 64) ? w_z[i * 128 + k] : b_z[k];
        s = fmaf(a, w_d0[k * 128 + j], s);
    }
    if (i < 64) {
        int c = j >> 4, kb = i >> 5, l = ((i >> 3) & 3) * 16 + (j & 15), e = i & 7;
        P_wc[(size_t)((c * 2 + kb) * 64 + l) * 8 + e] = f2bf(s);
    } else bzw[j] = s;
}

// ------------------------------------------------------------------ weight packs (6 weights, 1 launch)
// Wp[((c*KB+kb)*64+l)*8+e] = bf16(W[kb*32+(l>>4)*8+e][c*16+(l&15)])
__device__ __forceinline__ void pack_one(const float* __restrict__ W, ushort* __restrict__ P,
                                         int KI, int KO, int idx) {
    if (idx >= KI * KO) return;
    int e = idx & 7, l = (idx >> 3) & 63, t = idx >> 9;
    int KB = KI / 32;
    int c = t / KB, kb = t % KB;
    int k = kb * 32 + ((l >> 4) << 3) + e, col = c * 16 + (l & 15);
    P[idx] = f2bf(W[(size_t)k * KO + col]);
}

__global__ void megapack_kernel(const float* w_in, const float* w_mu0, const float* w_si0,
                                const float* w_mu, const float* w_si, const float* w_out,
                                ushort* P_in, ushort* P_mu0, ushort* P_si0,
                                ushort* P_mu, ushort* P_si, ushort* P_out) {
    int b = blockIdx.x, tid = threadIdx.x;
    if (b < 32)       pack_one(w_in,  P_in,  64, 128,  (b - 0)   * 256 + tid);
    else if (b < 96)  pack_one(w_mu0, P_mu0, 128, 128, (b - 32)  * 256 + tid);
    else if (b < 160) pack_one(w_si0, P_si0, 128, 128, (b - 96)  * 256 + tid);
    else if (b < 192) pack_one(w_mu,  P_mu,  128, 64,  (b - 160) * 256 + tid);
    else if (b < 224) pack_one(w_si,  P_si,  128, 64,  (b - 192) * 256 + tid);
    else              pack_one(w_out, P_out, 128, 128, (b - 224) * 256 + tid);
}

// ------------------------------------------------------------------ f32 -> bf16
__global__ void cvt8_kernel(const float* __restrict__ in, ushort* __restrict__ out, int n8) {
    int i = blockIdx.x * 256 + threadIdx.x;
    if (i >= n8) return;
    float4 a = ((const float4*)in)[i * 2];
    float4 b = ((const float4*)in)[i * 2 + 1];
    bf16x8 o;
    o[0] = (short)f2bf(a.x); o[1] = (short)f2bf(a.y);
    o[2] = (short)f2bf(a.z); o[3] = (short)f2bf(a.w);
    o[4] = (short)f2bf(b.x); o[5] = (short)f2bf(b.y);
    o[6] = (short)f2bf(b.z); o[7] = (short)f2bf(b.w);
    ((bf16x8*)out)[i] = o;
}

// ------------------------------------------------------------------ bf16 prop: out = Adjn@x + dinv^2*x  (wave per node)
// W = width (64/128). 2-deep edge pipeline, bf16 in/out.
template <int W>
__global__ __launch_bounds__(256) void bprop_kernel(const ushort* __restrict__ xb,
        ushort* __restrict__ out, const int* __restrict__ row_start,
        const int2* __restrict__ csr, const float* __restrict__ dinv, int N) {
    constexpr int L = W / 8, EPL = 64 / L;
    int wave = threadIdx.x >> 6, lane = threadIdx.x & 63;
    int node = blockIdx.x * 4 + wave;
    if (node >= N) return;
    int sub = lane / L, f8 = lane % L;
    int beg = row_start[node], end = row_start[node + 1];
    float d2 = dinv[node]; d2 *= d2;
    float a0[8] = {}, a1[8] = {};
    for (int base = beg; base < end; base += 2 * EPL) {
        int e0 = base + sub, e1 = base + EPL + sub;
        int2 p0 = csr[e0 < end ? e0 : 0];
        int2 p1 = csr[e1 < end ? e1 : 0];
        float w0 = (e0 < end) ? __int_as_float(p0.y) : 0.f;
        float w1 = (e1 < end) ? __int_as_float(p1.y) : 0.f;
        bf16x8 v0 = *(const bf16x8*)(xb + (size_t)p0.x * W + f8 * 8);
        bf16x8 v1 = *(const bf16x8*)(xb + (size_t)p1.x * W + f8 * 8);
        #pragma unroll
        for (int q = 0; q < 8; ++q) a0[q] = fmaf(w0, bf2f((ushort)v0[q]), a0[q]);
        #pragma unroll
        for (int q = 0; q < 8; ++q) a1[q] = fmaf(w1, bf2f((ushort)v1[q]), a1[q]);
    }
    float acc[8];
    #pragma unroll
    for (int q = 0; q < 8; ++q) acc[q] = a0[q] + a1[q];
    #pragma unroll
    for (int m = L; m < 64; m <<= 1) {
        #pragma unroll
        for (int q = 0; q < 8; ++q) acc[q] += __shfl_xor(acc[q], m);
    }
    if (sub != 0) return;
    bf16x8 sv = *(const bf16x8*)(xb + (size_t)node * W + f8 * 8);
    bf16x8 oz;
    #pragma unroll
    for (int q = 0; q < 8; ++q) oz[q] = (short)f2bf(fmaf(d2, bf2f((ushort)sv[q]), acc[q]));
    *(bf16x8*)(out + (size_t)node * W + f8 * 8) = oz;
}

// ------------------------------------------------------------------ K34: 128-prop of T=[tmu|tsi] -> mu, si, z
__global__ __launch_bounds__(256) void mssz_kernel(const ushort* __restrict__ T,
        const int* __restrict__ row_start, const int2* __restrict__ csr,
        const float* __restrict__ dinv, const float* __restrict__ b_mu,
        const float* __restrict__ b_si, const float* __restrict__ eps,
        float* __restrict__ M, float* __restrict__ S, ushort* __restrict__ zb, int N) {
    constexpr int L = 16, EPL = 4;
    int wave = threadIdx.x >> 6, lane = threadIdx.x & 63;
    int node = blockIdx.x * 4 + wave;
    if (node >= N) return;
    int sub = lane / L, f8 = lane % L;
    int beg = row_start[node], end = row_start[node + 1];
    float d2 = dinv[node]; d2 *= d2;
    float a0[8] = {}, a1[8] = {};
    for (int base = beg; base < end; base += 2 * EPL) {
        int e0 = base + sub, e1 = base + EPL + sub;
        int2 p0 = csr[e0 < end ? e0 : 0];
        int2 p1 = csr[e1 < end ? e1 : 0];
        float w0 = (e0 < end) ? __int_as_float(p0.y) : 0.f;
        float w1 = (e1 < end) ? __int_as_float(p1.y) : 0.f;
        bf16x8 v0 = *(const bf16x8*)(T + (size_t)p0.x * 128 + f8 * 8);
        bf16x8 v1 = *(const bf16x8*)(T + (size_t)p1.x * 128 + f8 * 8);
        #pragma unroll
        for (int q = 0; q < 8; ++q) a0[q] = fmaf(w0, bf2f((ushort)v0[q]), a0[q]);
        #pragma unroll
        for (int q = 0; q < 8; ++q) a1[q] = fmaf(w1, bf2f((ushort)v1[q]), a1[q]);
    }
    float acc[8];
    #pragma unroll
    for (int q = 0; q < 8; ++q) acc[q] = a0[q] + a1[q];
    #pragma unroll
    for (int m = 16; m < 64; m <<= 1) {
        #pragma unroll
        for (int q = 0; q < 8; ++q) acc[q] += __shfl_xor(acc[q], m);
    }
    if (sub != 0) return;
    bf16x8 sv = *(const bf16x8*)(T + (size_t)node * 128 + f8 * 8);
    #pragma unroll
    for (int q = 0; q < 8; ++q) acc[q] = fmaf(d2, bf2f((ushort)sv[q]), acc[q]);

    bool is_mu = (f8 < 8);
    const float* bp = is_mu ? b_mu : b_si;
    int o = (f8 & 7) * 8;
    float val[8];
    #pragma unroll
    for (int q = 0; q < 8; ++q) {
        float t = acc[q] + bp[o + q];
        val[q] = is_mu ? fmaxf(t, 0.f) : 1.f / (1.f + __expf(-t));
    }
    if (is_mu) {
        *(float4*)&M[(size_t)node * 64 + o]     = make_float4(val[0], val[1], val[2], val[3]);
        *(float4*)&M[(size_t)node * 64 + o + 4] = make_float4(val[4], val[5], val[6], val[7]);
    } else {
        *(float4*)&S[(size_t)node * 64 + o]     = make_float4(val[0], val[1], val[2], val[3]);
        *(float4*)&S[(size_t)node * 64 + o + 4] = make_float4(val[4], val[5], val[6], val[7]);
    }
    float oth[8];
    #pragma unroll
    for (int q = 0; q < 8; ++q) oth[q] = __shfl_xor(val[q], 8);
    if (is_mu) {   // lane holds mu (val) + si (oth): z = mu + si*eps
        float4 e0v = *(const float4*)&eps[(size_t)node * 64 + o];
        float4 e1v = *(const float4*)&eps[(size_t)node * 64 + o + 4];
        float ev[8] = {e0v.x, e0v.y, e0v.z, e0v.w, e1v.x, e1v.y, e1v.z, e1v.w};
        bf16x8 z;
        #pragma unroll
        for (int q = 0; q < 8; ++q) z[q] = (short)f2bf(fmaf(oth[q], ev[q], val[q]));
        *(bf16x8*)(zb + (size_t)node * 64 + o) = z;
    }
}

// ------------------------------------------------------------------ MFMA GEMM: out[N,·] = Xb[N,KI]@W + epilogue
// 4 waves; wave w owns rows blockIdx*64 + w*16. Runtime output row-stride.
// EPI: 0 none, 1 +bias, 2 +bias,relu, 3 relu(v + cvec[row]*bias + bias2).
// OUT: 0 bf16, 1 f32. Output staged via LDS for coalesced stores.
template <int KI, int KO, int EPI, int OUT>
__global__ __launch_bounds__(256) void mgemm_kernel(const ushort* __restrict__ Xb,
                                                    const bf16x8* __restrict__ Wp,
                                                    const float* __restrict__ bias,
                                                    const float* __restrict__ bias2,
                                                    const float* __restrict__ cvec,
                                                    void* __restrict__ outp, int ostride, int N) {
    constexpr int KB = KI / 32;
    constexpr int CT = KO / 16;
    constexpr size_t LSB = (OUT == 1) ? (size_t)64 * KO * 4 : (size_t)64 * KO * 2;
    __shared__ __align__(16) char LsRaw[LSB];

    int w = threadIdx.x >> 6, l = threadIdx.x & 63;
    int lr = l & 15, lk = l >> 4;
    int rowbase = blockIdx.x * 64;
    int r0 = rowbase + w * 16;

    int arow = r0 + lr; if (arow > N - 1) arow = N - 1;
    bf16x8 a[KB];
    const ushort* xp = Xb + (size_t)arow * KI + lk * 8;
    #pragma unroll
    for (int kb = 0; kb < KB; ++kb) a[kb] = *(const bf16x8*)(xp + kb * 32);

    float cv[4];
    if constexpr (EPI == 3) {
        #pragma unroll
        for (int r = 0; r < 4; ++r) {
            int rr = r0 + lk * 4 + r;
            cv[r] = cvec[rr < N ? rr : 0];
        }
    }

    #pragma unroll
    for (int c = 0; c < CT; ++c) {
        f32x4 acc = {0.f, 0.f, 0.f, 0.f};
        #pragma unroll
        for (int kb = 0; kb < KB; ++kb)
            acc = __builtin_amdgcn_mfma_f32_16x16x32_bf16(a[kb], Wp[((size_t)c * KB + kb) * 64 + l], acc, 0, 0, 0);
        int col = c * 16 + lr;
        float bv = 0.f, b2v = 0.f;
        if constexpr (EPI >= 1) bv = bias[col];
        if constexpr (EPI == 3) b2v = bias2[col];
        #pragma unroll
        for (int r = 0; r < 4; ++r) {
            float v = acc[r];
            if constexpr (EPI == 1) v += bv;
            if constexpr (EPI == 2) v = fmaxf(v + bv, 0.f);
            if constexpr (EPI == 3) v = fmaxf(v + cv[r] * bv + b2v, 0.f);
            int rl = w * 16 + lk * 4 + r;
            if constexpr (OUT == 0) ((ushort*)LsRaw)[(size_t)rl * KO + col] = f2bf(v);
            else                    ((float*)LsRaw)[(size_t)rl * KO + col] = v;
        }
    }
    __syncthreads();

    if constexpr (OUT == 0) {
        ushort* o = (ushort*)outp;
        constexpr int CH = 64 * KO / 8;
        for (int idx = threadIdx.x; idx < CH; idx += 256) {
            int row = idx / (KO / 8), c8 = idx % (KO / 8);
            if (rowbase + row < N)
                *(bf16x8*)(o + (size_t)(rowbase + row) * ostride + c8 * 8) = ((const bf16x8*)LsRaw)[idx];
        }
    } else {
        float* o = (float*)outp;
        constexpr int CH = 64 * KO / 4;
        for (int idx = threadIdx.x; idx < CH; idx += 256) {
            int row = idx / (KO / 4), c4 = idx % (KO / 4);
            if (rowbase + row < N)
                *(float4*)(o + (size_t)(rowbase + row) * ostride + c4 * 4) = ((const float4*)LsRaw)[idx];
        }
    }
}

// ------------------------------------------------------------------ launch
extern "C" void kernel_launch(void* const* d_in, const int* in_sizes, int n_in,
                              void* d_out, int out_size, void* d_ws, size_t ws_size,
                              hipStream_t stream) {
    const float* x    = (const float*)d_in[0];
    const float* eps  = (const float*)d_in[1];
    const int*   ei   = (const int*)d_in[2];
    const float* w_in  = (const float*)d_in[3];  const float* b_in  = (const float*)d_in[4];
    const float* w_mu0 = (const float*)d_in[5];  const float* b_mu0 = (const float*)d_in[6];
    const float* w_mu  = (const float*)d_in[7];  const float* b_mu  = (const float*)d_in[8];
    const float* w_si0 = (const float*)d_in[9];  const float* b_si0 = (const float*)d_in[10];
    const float* w_si  = (const float*)d_in[11]; const float* b_si  = (const float*)d_in[12];
    const float* w_z   = (const float*)d_in[13]; const float* b_z   = (const float*)d_in[14];
    const float* w_d0  = (const float*)d_in[15]; const float* b_d0  = (const float*)d_in[16];
    const float* w_out = (const float*)d_in[17]; const float* b_out = (const float*)d_in[18];

    const int N = in_sizes[0] / 64;
    const int E = in_sizes[2] / 2;
    const int* srcI = ei;
    const int* dstI = ei + E;

    int shift = 4;
    while (((N >> shift) + 1) > 8192) shift++;
    const int NB = (N >> shift) + 1;

    auto align = [](size_t v) { return (v + 255) & ~(size_t)255; };
    char* wsp = (char*)d_ws;
    size_t off = 0;
    int*    deg       = (int*)(wsp + off);    size_t deg_off = off; off = align(off + (size_t)N * 4);
    int*    bc0       = (int*)(wsp + off);    off = align(off + (size_t)NB * 4);
    int*    bc1       = (int*)(wsp + off);    off = align(off + (size_t)NB * 4);
    size_t  zero_span = off - deg_off;
    float*  cvec      = (float*)(wsp + off);  off = align(off + (size_t)N * 4);
    int*    row_start = (int*)(wsp + off);    off = align(off + (size_t)(N + 1) * 4);
    int*    bin_start = (int*)(wsp + off);    off = align(off + (size_t)(NB + 1) * 4);
    int*    bsum      = (int*)(wsp + off);    off = align(off + 1024 * 4);
    float*  dinv      = (float*)(wsp + off);  off = align(off + (size_t)N * 4);
    float*  bzw       = (float*)(wsp + off);  off = align(off + 128 * 4);
    ushort* P_in      = (ushort*)(wsp + off); off = align(off + 64 * 128 * 2);
    ushort* P_mu0     = (ushort*)(wsp + off); off = align(off + 128 * 128 * 2);
    ushort* P_si0     = (ushort*)(wsp + off); off = align(off + 128 * 128 * 2);
    ushort* P_mu      = (ushort*)(wsp + off); off = align(off + 128 * 64 * 2);
    ushort* P_si      = (ushort*)(wsp + off); off = align(off + 128 * 64 * 2);
    ushort* P_wc      = (ushort*)(wsp + off); off = align(off + 64 * 128 * 2);
    ushort* P_out     = (ushort*)(wsp + off); off = align(off + 128 * 128 * 2);
    int2*   csr       = (int2*)(wsp + off);   off = align(off + (size_t)E * 8);
    int2*   ebuf      = (int2*)(wsp + off);   off = align(off + (size_t)E * 8);  // alias: xb after place2
    ushort* xb        = (ushort*)ebuf;        // [N,64] bf16 x, later ppz
    ushort* B1        = (ushort*)(wsp + off); off = align(off + (size_t)N * 128 * 2);
    ushort* B1lo = B1;                        // [N,64]
    ushort* B1hi = B1 + (size_t)N * 64;       // [N,64]

    float* Cc = (float*)d_out;               // logits f32 [N,128] (final)
    float* M  = Cc + (size_t)N * 128;        // mu f32 (final)
    float* S  = M + (size_t)N * 64;          // si f32 (final)
    ushort* CcLo = (ushort*)Cc;              // bf16 [N,128] scratch: h, later r2
    ushort* CcHi = (ushort*)(Cc + (size_t)N * 64);  // bf16 [N,128] scratch: T=[tmu|tsi]
    ushort* Db   = (ushort*)M;               // bf16 [N,128] scratch: ph (dead before mssz writes M)

    const int TB = 256;
    hipMemsetAsync(deg, 0, zero_span, stream);
    counts_kernel<<<256, 1024, 0, stream>>>(dstI, deg, bc0, E, NB, shift);
    dinv_kernel<<<(N + TB - 1) / TB, TB, 0, stream>>>(deg, dinv, N);
    int nbN = (N + 1023) / 1024;
    scan_block_kernel<<<nbN, 1024, 0, stream>>>(deg, row_start, bsum, N);
    scan_partials_kernel<<<1, 1024, 0, stream>>>(bsum, nbN);
    scan_add_kernel<<<nbN, 1024, 0, stream>>>(row_start, bsum, N, E);
    int nbB = (NB + 1023) / 1024;
    scan_block_kernel<<<nbB, 1024, 0, stream>>>(bc0, bin_start, bsum, NB);
    scan_partials_kernel<<<1, 1024, 0, stream>>>(bsum, nbB);
    scan_add_kernel<<<nbB, 1024, 0, stream>>>(bin_start, bsum, NB, E);
    hipMemsetAsync(deg, 0, (size_t)N * 4, stream);   // deg reused as place counter
    scatter_kernel<<<(E + TB - 1) / TB, TB, 0, stream>>>(srcI, dstI, bin_start, bc1, ebuf, E, shift);
    place2_kernel<<<(E + TB - 1) / TB, TB, 0, stream>>>(ebuf, row_start, deg, csr, dinv, E);
    rowsum_kernel<<<(N + TB - 1) / TB, TB, 0, stream>>>(csr, row_start, dinv, cvec, N);
    wcpack_kernel<<<(65 * 128 + 255) / 256, 256, 0, stream>>>(w_z, b_z, w_d0, P_wc, bzw);
    megapack_kernel<<<288, 256, 0, stream>>>(w_in, w_mu0, w_si0, w_mu, w_si, w_out,
                                             P_in, P_mu0, P_si0, P_mu, P_si, P_out);
    cvt8_kernel<<<((N * 8) + 255) / 256, 256, 0, stream>>>(x, xb, N * 8);  // ebuf alias dead

    int PG = (N + 3) / 4;
    int GB = (N + 63) / 64;

    // 1. px = P(x) -> B1lo [64]
    bprop_kernel<64><<<PG, 256, 0, stream>>>(xb, B1lo, row_start, csr, dinv, N);
    // 2. h = relu(px@w_in + b) -> CcLo [128]
    mgemm_kernel<64, 128, 2, 0><<<GB, 256, 0, stream>>>(B1lo, (const bf16x8*)P_in, b_in, nullptr, nullptr, CcLo, 128, N);
    // 3. ph = P(h) -> Db [128]
    bprop_kernel<128><<<PG, 256, 0, stream>>>(CcLo, Db, row_start, csr, dinv, N);
    // 4. mu1 = relu(ph@w_mu0 + b) -> B1 [128] (px dead)
    mgemm_kernel<128, 128, 2, 0><<<GB, 256, 0, stream>>>(Db, (const bf16x8*)P_mu0, b_mu0, nullptr, nullptr, B1, 128, N);
    // 5. tmu = mu1@w_mu -> T cols 0..63 (CcHi, stride 128)
    mgemm_kernel<128, 64, 0, 0><<<GB, 256, 0, stream>>>(B1, (const bf16x8*)P_mu, nullptr, nullptr, nullptr, CcHi, 128, N);
    // 6. si1 = relu(ph@w_si0 + b) -> CcLo [128] (h dead)
    mgemm_kernel<128, 128, 2, 0><<<GB, 256, 0, stream>>>(Db, (const bf16x8*)P_si0, b_si0, nullptr, nullptr, CcLo, 128, N);
    // 7. tsi = si1@w_si -> T cols 64..127
    mgemm_kernel<128, 64, 0, 0><<<GB, 256, 0, stream>>>(CcLo, (const bf16x8*)P_si, nullptr, nullptr, nullptr, CcHi + 64, 128, N);
    // 8. mssz: prop T -> mu (M f32), si (S f32), z -> B1lo bf16 (mu1/ph dead)
    mssz_kernel<<<PG, 256, 0, stream>>>(CcHi, row_start, csr, dinv, b_mu, b_si, eps, M, S, B1lo, N);
    // 9. pz = P(z) -> B1hi [64]
    bprop_kernel<64><<<PG, 256, 0, stream>>>(B1lo, B1hi, row_start, csr, dinv, N);
    // 10. ppz = P(pz) -> xb region (x dead)
    bprop_kernel<64><<<PG, 256, 0, stream>>>(B1hi, xb, row_start, csr, dinv, N);
    // 11. r2 = relu(ppz@Wc + cvec*bzw + b_d0) -> CcLo [128] (si1 dead)
    mgemm_kernel<64, 128, 3, 0><<<GB, 256, 0, stream>>>(xb, (const bf16x8*)P_wc, bzw, b_d0, cvec, CcLo, 128, N);
    // 12. pr2 = P(r2) -> B1 [128] (z/pz dead)
    bprop_kernel<128><<<PG, 256, 0, stream>>>(CcLo, B1, row_start, csr, dinv, N);
    // 13. logits = pr2@w_out + b_out -> Cc f32 (final; reads B1 only)
    mgemm_kernel<128, 128, 1, 1><<<GB, 256, 0, stream>>>(B1, (const bf16x8*)P_out, b_out, nullptr, nullptr, Cc, 128, N);
}

// Round 7
// 673.585 us; speedup vs baseline: 1.2012x; 1.0023x over previous
//
#include <hip/hip_runtime.h>

// VGAE: 8 GCN layers, N=100000, E=1.6M, dims 64/128 — bf16 + MFMA.
// GCN(x,W,b) = P(x)@W + b, P(y) = Adjn@y + dinv^2*y (linear, commutes with W).
// Props: wave-per-node, edge-PAIR inner loop via v_dot2_f32_bf16 + v_perm packing
// (bf16 elementwise cvt+fma was VALU-bound at 58% VALUBusy in r6).
// Binned CSR build; decoder 1-2 fused via Wc = w_z@w_d0.

typedef short bf16x8 __attribute__((ext_vector_type(8)));
typedef float f32x4 __attribute__((ext_vector_type(4)));

__device__ __forceinline__ ushort f2bf(float f) {           // RNE
    uint x = __float_as_uint(f);
    uint r = x + 0x7FFFu + ((x >> 16) & 1u);
    return (ushort)(r >> 16);
}
__device__ __forceinline__ float bf2f(ushort h) {
    return __uint_as_float(((uint)h) << 16);
}
__device__ __forceinline__ float dot2bf(uint a, uint b, float c) {
    float d;
    asm("v_dot2_f32_bf16 %0, %1, %2, %3" : "=v"(d) : "v"(a), "v"(b), "v"(c));
    return d;
}

// ------------------------------------------------------------------ counts: deg + binned histogram
__global__ __launch_bounds__(1024) void counts_kernel(const int* __restrict__ dst,
        int* __restrict__ deg, int* __restrict__ bc0, int E, int NB, int shift) {
    __shared__ int h[8192];
    for (int j = threadIdx.x; j < NB; j += 1024) h[j] = 0;
    __syncthreads();
    int stride = gridDim.x * 1024;
    for (int i = blockIdx.x * 1024 + threadIdx.x; i < E; i += stride) {
        int d = dst[i];
        atomicAdd(&deg[d], 1);
        atomicAdd(&h[d >> shift], 1);
    }
    __syncthreads();
    for (int j = threadIdx.x; j < NB; j += 1024) {
        int v = h[j];
        if (v) atomicAdd(&bc0[j], v);
    }
}

__global__ void dinv_kernel(const int* __restrict__ deg, float* __restrict__ dinv, int N) {
    int i = blockIdx.x * blockDim.x + threadIdx.x;
    if (i < N) dinv[i] = rsqrtf((float)(deg[i] + 1));
}

// ------------------------------------------------------------------ scan
__global__ __launch_bounds__(1024) void scan_block_kernel(const int* __restrict__ in,
                                                          int* __restrict__ out,
                                                          int* __restrict__ bsum, int n) {
    __shared__ int s[1024];
    int i = blockIdx.x * 1024 + threadIdx.x;
    int v = (i < n) ? in[i] : 0;
    s[threadIdx.x] = v;
    __syncthreads();
    for (int off = 1; off < 1024; off <<= 1) {
        int t = (threadIdx.x >= off) ? s[threadIdx.x - off] : 0;
        __syncthreads();
        s[threadIdx.x] += t;
        __syncthreads();
    }
    if (i < n) out[i] = s[threadIdx.x] - v;
    if (threadIdx.x == 1023) bsum[blockIdx.x] = s[1023];
}

__global__ __launch_bounds__(1024) void scan_partials_kernel(int* __restrict__ bsum, int nb) {
    __shared__ int s[1024];
    int v = (threadIdx.x < nb) ? bsum[threadIdx.x] : 0;
    s[threadIdx.x] = v;
    __syncthreads();
    for (int off = 1; off < 1024; off <<= 1) {
        int t = (threadIdx.x >= off) ? s[threadIdx.x - off] : 0;
        __syncthreads();
        s[threadIdx.x] += t;
        __syncthreads();
    }
    if (threadIdx.x < nb) bsum[threadIdx.x] = s[threadIdx.x] - v;
}

__global__ __launch_bounds__(1024) void scan_add_kernel(int* __restrict__ arr,
                                                        const int* __restrict__ bsum, int n, int total) {
    int i = blockIdx.x * 1024 + threadIdx.x;
    if (i < n) arr[i] += bsum[blockIdx.x];
    if (i == 0) arr[n] = total;
}

// ------------------------------------------------------------------ bin scatter + place
__global__ void scatter_kernel(const int* __restrict__ src, const int* __restrict__ dst,
                               const int* __restrict__ bin_start, int* __restrict__ bc1,
                               int2* __restrict__ ebuf, int E, int shift) {
    int i = blockIdx.x * blockDim.x + threadIdx.x;
    if (i < E) {
        int d = dst[i];
        int b = d >> shift;
        int pos = bin_start[b] + atomicAdd(&bc1[b], 1);
        ebuf[pos] = make_int2(src[i], d);
    }
}

// csr entry: {src, bf16(weight) in low 16 bits}
__global__ void place2_kernel(const int2* __restrict__ ebuf, const int* __restrict__ row_start,
                              int* __restrict__ cnt, int2* __restrict__ csr,
                              const float* __restrict__ dinv, int E) {
    int i = blockIdx.x * blockDim.x + threadIdx.x;
    if (i < E) {
        int2 e = ebuf[i];
        int pos = row_start[e.y] + atomicAdd(&cnt[e.y], 1);
        csr[pos] = make_int2(e.x, (int)(uint)f2bf(dinv[e.x] * dinv[e.y]));
    }
}

// ------------------------------------------------------------------ cvec[j] = dinv_j^2 + sum_w (bf16 weights, consistent with props)
__global__ void rowsum_kernel(const int2* __restrict__ csr, const int* __restrict__ row_start,
                              const float* __restrict__ dinv, float* __restrict__ cvec, int N) {
    int j = blockIdx.x * blockDim.x + threadIdx.x;
    if (j >= N) return;
    float s = dinv[j] * dinv[j];
    int b = row_start[j], e = row_start[j + 1];
    for (int k = b; k < e; ++k) s += bf2f((ushort)((uint)csr[k].y & 0xFFFFu));
    cvec[j] = s;
}

// ------------------------------------------------------------------ Wc = w_z@w_d0 packed bf16, bzw = b_z@w_d0
__global__ void wcpack_kernel(const float* __restrict__ w_z, const float* __restrict__ b_z,
                              const float* __restrict__ w_d0,
                              ushort* __restrict__ P_wc, float* __restrict__ bzw) {
    int o = blockIdx.x * 256 + threadIdx.x;
    if (o >= 65 * 128) return;
    int i = o >> 7, j = o & 127;
    float s = 0.f;
    for (int k = 0; k < 128; ++k) {
        float a = (i < 64) ? w_z[i * 128 + k] : b_z[k];
        s = fmaf(a, w_d0[k * 128 + j], s);
    }
    if (i < 64) {
        int c = j >> 4, kb = i >> 5, l = ((i >> 3) & 3) * 16 + (j & 15), e = i & 7;
        P_wc[(size_t)((c * 2 + kb) * 64 + l) * 8 + e] = f2bf(s);
    } else bzw[j] = s;
}

// ------------------------------------------------------------------ weight packs (6 weights, 1 launch)
__device__ __forceinline__ void pack_one(const float* __restrict__ W, ushort* __restrict__ P,
                                         int KI, int KO, int idx) {
    if (idx >= KI * KO) return;
    int e = idx & 7, l = (idx >> 3) & 63, t = idx >> 9;
    int KB = KI / 32;
    int c = t / KB, kb = t % KB;
    int k = kb * 32 + ((l >> 4) << 3) + e, col = c * 16 + (l & 15);
    P[idx] = f2bf(W[(size_t)k * KO + col]);
}

__global__ void megapack_kernel(const float* w_in, const float* w_mu0, const float* w_si0,
                                const float* w_mu, const float* w_si, const float* w_out,
                                ushort* P_in, ushort* P_mu0, ushort* P_si0,
                                ushort* P_mu, ushort* P_si, ushort* P_out) {
    int b = blockIdx.x, tid = threadIdx.x;
    if (b < 32)       pack_one(w_in,  P_in,  64, 128,  (b - 0)   * 256 + tid);
    else if (b < 96)  pack_one(w_mu0, P_mu0, 128, 128, (b - 32)  * 256 + tid);
    else if (b < 160) pack_one(w_si0, P_si0, 128, 128, (b - 96)  * 256 + tid);
    else if (b < 192) pack_one(w_mu,  P_mu,  128, 64,  (b - 160) * 256 + tid);
    else if (b < 224) pack_one(w_si,  P_si,  128, 64,  (b - 192) * 256 + tid);
    else              pack_one(w_out, P_out, 128, 128, (b - 224) * 256 + tid);
}

// ------------------------------------------------------------------ f32 -> bf16
__global__ void cvt8_kernel(const float* __restrict__ in, ushort* __restrict__ out, int n8) {
    int i = blockIdx.x * 256 + threadIdx.x;
    if (i >= n8) return;
    float4 a = ((const float4*)in)[i * 2];
    float4 b = ((const float4*)in)[i * 2 + 1];
    bf16x8 o;
    o[0] = (short)f2bf(a.x); o[1] = (short)f2bf(a.y);
    o[2] = (short)f2bf(a.z); o[3] = (short)f2bf(a.w);
    o[4] = (short)f2bf(b.x); o[5] = (short)f2bf(b.y);
    o[6] = (short)f2bf(b.z); o[7] = (short)f2bf(b.w);
    ((bf16x8*)out)[i] = o;
}

// ------------------------------------------------------------------ gather core: one edge PAIR per sub-slot per iter.
// Returns 8 f32 partial sums in acc (features f8*8..+7), cross-sub reduced.
template <int W>
__device__ __forceinline__ void gather_pairs(float* acc, const ushort* __restrict__ xb,
        const int2* __restrict__ csr, int node, int beg, int end, int sub, int f8) {
    for (int base = beg; base < end; base += 2 * (64 / (W / 8))) {
        int e0 = base + 2 * sub, e1 = e0 + 1;
        int2 p0 = csr[e0 < end ? e0 : beg];
        int2 p1 = csr[e1 < end ? e1 : beg];
        int s0 = (e0 < end) ? p0.x : node;
        int s1 = (e1 < end) ? p1.x : node;
        uint w0 = (e0 < end) ? (uint)p0.y : 0u;
        uint w1 = (e1 < end) ? (uint)p1.y : 0u;
        uint wpk = __builtin_amdgcn_perm(w1, w0, 0x05040100u);   // (w0 lo16, w1 hi16)
        uint4 v0 = *(const uint4*)(xb + (size_t)s0 * W + f8 * 8);
        uint4 v1 = *(const uint4*)(xb + (size_t)s1 * W + f8 * 8);
        uint t;
        t = __builtin_amdgcn_perm(v1.x, v0.x, 0x05040100u); acc[0] = dot2bf(t, wpk, acc[0]);
        t = __builtin_amdgcn_perm(v1.x, v0.x, 0x07060302u); acc[1] = dot2bf(t, wpk, acc[1]);
        t = __builtin_amdgcn_perm(v1.y, v0.y, 0x05040100u); acc[2] = dot2bf(t, wpk, acc[2]);
        t = __builtin_amdgcn_perm(v1.y, v0.y, 0x07060302u); acc[3] = dot2bf(t, wpk, acc[3]);
        t = __builtin_amdgcn_perm(v1.z, v0.z, 0x05040100u); acc[4] = dot2bf(t, wpk, acc[4]);
        t = __builtin_amdgcn_perm(v1.z, v0.z, 0x07060302u); acc[5] = dot2bf(t, wpk, acc[5]);
        t = __builtin_amdgcn_perm(v1.w, v0.w, 0x05040100u); acc[6] = dot2bf(t, wpk, acc[6]);
        t = __builtin_amdgcn_perm(v1.w, v0.w, 0x07060302u); acc[7] = dot2bf(t, wpk, acc[7]);
    }
}

// ------------------------------------------------------------------ bf16 prop: out = Adjn@x + dinv^2*x (wave per node)
template <int W>
__global__ __launch_bounds__(256) void bprop_kernel(const ushort* __restrict__ xb,
        ushort* __restrict__ out, const int* __restrict__ row_start,
        const int2* __restrict__ csr, const float* __restrict__ dinv, int N) {
    constexpr int L = W / 8;
    int wave = threadIdx.x >> 6, lane = threadIdx.x & 63;
    int node = blockIdx.x * 4 + wave;
    if (node >= N) return;
    int sub = lane / L, f8 = lane % L;
    int beg = row_start[node], end = row_start[node + 1];
    float d2 = dinv[node]; d2 *= d2;
    float acc[8] = {};
    gather_pairs<W>(acc, xb, csr, node, beg, end, sub, f8);
    #pragma unroll
    for (int m = L; m < 64; m <<= 1) {
        #pragma unroll
        for (int q = 0; q < 8; ++q) acc[q] += __shfl_xor(acc[q], m);
    }
    if (sub != 0) return;
    bf16x8 sv = *(const bf16x8*)(xb + (size_t)node * W + f8 * 8);
    bf16x8 oz;
    #pragma unroll
    for (int q = 0; q < 8; ++q) oz[q] = (short)f2bf(fmaf(d2, bf2f((ushort)sv[q]), acc[q]));
    *(bf16x8*)(out + (size_t)node * W + f8 * 8) = oz;
}

// ------------------------------------------------------------------ mssz: 128-prop of T=[tmu|tsi] -> mu, si, z
__global__ __launch_bounds__(256) void mssz_kernel(const ushort* __restrict__ T,
        const int* __restrict__ row_start, const int2* __restrict__ csr,
        const float* __restrict__ dinv, const float* __restrict__ b_mu,
        const float* __restrict__ b_si, const float* __restrict__ eps,
        float* __restrict__ M, float* __restrict__ S, ushort* __restrict__ zb, int N) {
    constexpr int L = 16;
    int wave = threadIdx.x >> 6, lane = threadIdx.x & 63;
    int node = blockIdx.x * 4 + wave;
    if (node >= N) return;
    int sub = lane / L, f8 = lane % L;
    int beg = row_start[node], end = row_start[node + 1];
    float d2 = dinv[node]; d2 *= d2;
    float acc[8] = {};
    gather_pairs<128>(acc, T, csr, node, beg, end, sub, f8);
    #pragma unroll
    for (int m = 16; m < 64; m <<= 1) {
        #pragma unroll
        for (int q = 0; q < 8; ++q) acc[q] += __shfl_xor(acc[q], m);
    }
    if (sub != 0) return;
    bf16x8 sv = *(const bf16x8*)(T + (size_t)node * 128 + f8 * 8);
    #pragma unroll
    for (int q = 0; q < 8; ++q) acc[q] = fmaf(d2, bf2f((ushort)sv[q]), acc[q]);

    bool is_mu = (f8 < 8);
    const float* bp = is_mu ? b_mu : b_si;
    int o = (f8 & 7) * 8;
    float val[8];
    #pragma unroll
    for (int q = 0; q < 8; ++q) {
        float t = acc[q] + bp[o + q];
        val[q] = is_mu ? fmaxf(t, 0.f) : 1.f / (1.f + __expf(-t));
    }
    if (is_mu) {
        *(float4*)&M[(size_t)node * 64 + o]     = make_float4(val[0], val[1], val[2], val[3]);
        *(float4*)&M[(size_t)node * 64 + o + 4] = make_float4(val[4], val[5], val[6], val[7]);
    } else {
        *(float4*)&S[(size_t)node * 64 + o]     = make_float4(val[0], val[1], val[2], val[3]);
        *(float4*)&S[(size_t)node * 64 + o + 4] = make_float4(val[4], val[5], val[6], val[7]);
    }
    float oth[8];
    #pragma unroll
    for (int q = 0; q < 8; ++q) oth[q] = __shfl_xor(val[q], 8);
    if (is_mu) {   // lane holds mu (val) + si (oth): z = mu + si*eps
        float4 e0v = *(const float4*)&eps[(size_t)node * 64 + o];
        float4 e1v = *(const float4*)&eps[(size_t)node * 64 + o + 4];
        float ev[8] = {e0v.x, e0v.y, e0v.z, e0v.w, e1v.x, e1v.y, e1v.z, e1v.w};
        bf16x8 z;
        #pragma unroll
        for (int q = 0; q < 8; ++q) z[q] = (short)f2bf(fmaf(oth[q], ev[q], val[q]));
        *(bf16x8*)(zb + (size_t)node * 64 + o) = z;
    }
}

// ------------------------------------------------------------------ MFMA GEMM: out[N,·] = Xb[N,KI]@W + epilogue
// EPI: 0 none, 1 +bias, 2 +bias,relu, 3 relu(v + cvec[row]*bias + bias2).
// OUT: 0 bf16, 1 f32. Output staged via LDS for coalesced stores.
template <int KI, int KO, int EPI, int OUT>
__global__ __launch_bounds__(256) void mgemm_kernel(const ushort* __restrict__ Xb,
                                                    const bf16x8* __restrict__ Wp,
                                                    const float* __restrict__ bias,
                                                    const float* __restrict__ bias2,
                                                    const float* __restrict__ cvec,
                                                    void* __restrict__ outp, int ostride, int N) {
    constexpr int KB = KI / 32;
    constexpr int CT = KO / 16;
    constexpr size_t LSB = (OUT == 1) ? (size_t)64 * KO * 4 : (size_t)64 * KO * 2;
    __shared__ __align__(16) char LsRaw[LSB];

    int w = threadIdx.x >> 6, l = threadIdx.x & 63;
    int lr = l & 15, lk = l >> 4;
    int rowbase = blockIdx.x * 64;
    int r0 = rowbase + w * 16;

    int arow = r0 + lr; if (arow > N - 1) arow = N - 1;
    bf16x8 a[KB];
    const ushort* xp = Xb + (size_t)arow * KI + lk * 8;
    #pragma unroll
    for (int kb = 0; kb < KB; ++kb) a[kb] = *(const bf16x8*)(xp + kb * 32);

    float cv[4];
    if constexpr (EPI == 3) {
        #pragma unroll
        for (int r = 0; r < 4; ++r) {
            int rr = r0 + lk * 4 + r;
            cv[r] = cvec[rr < N ? rr : 0];
        }
    }

    #pragma unroll
    for (int c = 0; c < CT; ++c) {
        f32x4 acc = {0.f, 0.f, 0.f, 0.f};
        #pragma unroll
        for (int kb = 0; kb < KB; ++kb)
            acc = __builtin_amdgcn_mfma_f32_16x16x32_bf16(a[kb], Wp[((size_t)c * KB + kb) * 64 + l], acc, 0, 0, 0);
        int col = c * 16 + lr;
        float bv = 0.f, b2v = 0.f;
        if constexpr (EPI >= 1) bv = bias[col];
        if constexpr (EPI == 3) b2v = bias2[col];
        #pragma unroll
        for (int r = 0; r < 4; ++r) {
            float v = acc[r];
            if constexpr (EPI == 1) v += bv;
            if constexpr (EPI == 2) v = fmaxf(v + bv, 0.f);
            if constexpr (EPI == 3) v = fmaxf(v + cv[r] * bv + b2v, 0.f);
            int rl = w * 16 + lk * 4 + r;
            if constexpr (OUT == 0) ((ushort*)LsRaw)[(size_t)rl * KO + col] = f2bf(v);
            else                    ((float*)LsRaw)[(size_t)rl * KO + col] = v;
        }
    }
    __syncthreads();

    if constexpr (OUT == 0) {
        ushort* o = (ushort*)outp;
        constexpr int CH = 64 * KO / 8;
        for (int idx = threadIdx.x; idx < CH; idx += 256) {
            int row = idx / (KO / 8), c8 = idx % (KO / 8);
            if (rowbase + row < N)
                *(bf16x8*)(o + (size_t)(rowbase + row) * ostride + c8 * 8) = ((const bf16x8*)LsRaw)[idx];
        }
    } else {
        float* o = (float*)outp;
        constexpr int CH = 64 * KO / 4;
        for (int idx = threadIdx.x; idx < CH; idx += 256) {
            int row = idx / (KO / 4), c4 = idx % (KO / 4);
            if (rowbase + row < N)
                *(float4*)(o + (size_t)(rowbase + row) * ostride + c4 * 4) = ((const float4*)LsRaw)[idx];
        }
    }
}

// ------------------------------------------------------------------ launch
extern "C" void kernel_launch(void* const* d_in, const int* in_sizes, int n_in,
                              void* d_out, int out_size, void* d_ws, size_t ws_size,
                              hipStream_t stream) {
    const float* x    = (const float*)d_in[0];
    const float* eps  = (const float*)d_in[1];
    const int*   ei   = (const int*)d_in[2];
    const float* w_in  = (const float*)d_in[3];  const float* b_in  = (const float*)d_in[4];
    const float* w_mu0 = (const float*)d_in[5];  const float* b_mu0 = (const float*)d_in[6];
    const float* w_mu  = (const float*)d_in[7];  const float* b_mu  = (const float*)d_in[8];
    const float* w_si0 = (const float*)d_in[9];  const float* b_si0 = (const float*)d_in[10];
    const float* w_si  = (const float*)d_in[11]; const float* b_si  = (const float*)d_in[12];
    const float* w_z   = (const float*)d_in[13]; const float* b_z   = (const float*)d_in[14];
    const float* w_d0  = (const float*)d_in[15]; const float* b_d0  = (const float*)d_in[16];
    const float* w_out = (const float*)d_in[17]; const float* b_out = (const float*)d_in[18];

    const int N = in_sizes[0] / 64;
    const int E = in_sizes[2] / 2;
    const int* srcI = ei;
    const int* dstI = ei + E;

    int shift = 4;
    while (((N >> shift) + 1) > 8192) shift++;
    const int NB = (N >> shift) + 1;

    auto align = [](size_t v) { return (v + 255) & ~(size_t)255; };
    char* wsp = (char*)d_ws;
    size_t off = 0;
    int*    deg       = (int*)(wsp + off);    size_t deg_off = off; off = align(off + (size_t)N * 4);
    int*    bc0       = (int*)(wsp + off);    off = align(off + (size_t)NB * 4);
    int*    bc1       = (int*)(wsp + off);    off = align(off + (size_t)NB * 4);
    size_t  zero_span = off - deg_off;
    float*  cvec      = (float*)(wsp + off);  off = align(off + (size_t)N * 4);
    int*    row_start = (int*)(wsp + off);    off = align(off + (size_t)(N + 1) * 4);
    int*    bin_start = (int*)(wsp + off);    off = align(off + (size_t)(NB + 1) * 4);
    int*    bsum      = (int*)(wsp + off);    off = align(off + 1024 * 4);
    float*  dinv      = (float*)(wsp + off);  off = align(off + (size_t)N * 4);
    float*  bzw       = (float*)(wsp + off);  off = align(off + 128 * 4);
    ushort* P_in      = (ushort*)(wsp + off); off = align(off + 64 * 128 * 2);
    ushort* P_mu0     = (ushort*)(wsp + off); off = align(off + 128 * 128 * 2);
    ushort* P_si0     = (ushort*)(wsp + off); off = align(off + 128 * 128 * 2);
    ushort* P_mu      = (ushort*)(wsp + off); off = align(off + 128 * 64 * 2);
    ushort* P_si      = (ushort*)(wsp + off); off = align(off + 128 * 64 * 2);
    ushort* P_wc      = (ushort*)(wsp + off); off = align(off + 64 * 128 * 2);
    ushort* P_out     = (ushort*)(wsp + off); off = align(off + 128 * 128 * 2);
    int2*   csr       = (int2*)(wsp + off);   off = align(off + (size_t)E * 8);
    int2*   ebuf      = (int2*)(wsp + off);   off = align(off + (size_t)E * 8);  // alias: xb after place2
    ushort* xb        = (ushort*)ebuf;        // [N,64] bf16 x, later ppz
    ushort* B1        = (ushort*)(wsp + off); off = align(off + (size_t)N * 128 * 2);
    ushort* B1lo = B1;                        // [N,64]
    ushort* B1hi = B1 + (size_t)N * 64;       // [N,64]

    float* Cc = (float*)d_out;               // logits f32 [N,128] (final)
    float* M  = Cc + (size_t)N * 128;        // mu f32 (final)
    float* S  = M + (size_t)N * 64;          // si f32 (final)
    ushort* CcLo = (ushort*)Cc;              // bf16 [N,128] scratch: h, later r2
    ushort* CcHi = (ushort*)(Cc + (size_t)N * 64);  // bf16 [N,128] scratch: T=[tmu|tsi]
    ushort* Db   = (ushort*)M;               // bf16 [N,128] scratch: ph (dead before mssz writes M)

    const int TB = 256;
    hipMemsetAsync(deg, 0, zero_span, stream);
    counts_kernel<<<256, 1024, 0, stream>>>(dstI, deg, bc0, E, NB, shift);
    dinv_kernel<<<(N + TB - 1) / TB, TB, 0, stream>>>(deg, dinv, N);
    int nbN = (N + 1023) / 1024;
    scan_block_kernel<<<nbN, 1024, 0, stream>>>(deg, row_start, bsum, N);
    scan_partials_kernel<<<1, 1024, 0, stream>>>(bsum, nbN);
    scan_add_kernel<<<nbN, 1024, 0, stream>>>(row_start, bsum, N, E);
    int nbB = (NB + 1023) / 1024;
    scan_block_kernel<<<nbB, 1024, 0, stream>>>(bc0, bin_start, bsum, NB);
    scan_partials_kernel<<<1, 1024, 0, stream>>>(bsum, nbB);
    scan_add_kernel<<<nbB, 1024, 0, stream>>>(bin_start, bsum, NB, E);
    hipMemsetAsync(deg, 0, (size_t)N * 4, stream);   // deg reused as place counter
    scatter_kernel<<<(E + TB - 1) / TB, TB, 0, stream>>>(srcI, dstI, bin_start, bc1, ebuf, E, shift);
    place2_kernel<<<(E + TB - 1) / TB, TB, 0, stream>>>(ebuf, row_start, deg, csr, dinv, E);
    rowsum_kernel<<<(N + TB - 1) / TB, TB, 0, stream>>>(csr, row_start, dinv, cvec, N);
    wcpack_kernel<<<(65 * 128 + 255) / 256, 256, 0, stream>>>(w_z, b_z, w_d0, P_wc, bzw);
    megapack_kernel<<<288, 256, 0, stream>>>(w_in, w_mu0, w_si0, w_mu, w_si, w_out,
                                             P_in, P_mu0, P_si0, P_mu, P_si, P_out);
    cvt8_kernel<<<((N * 8) + 255) / 256, 256, 0, stream>>>(x, xb, N * 8);  // ebuf alias dead

    int PG = (N + 3) / 4;
    int GB = (N + 63) / 64;

    // 1. px = P(x) -> B1lo [64]
    bprop_kernel<64><<<PG, 256, 0, stream>>>(xb, B1lo, row_start, csr, dinv, N);
    // 2. h = relu(px@w_in + b) -> CcLo [128]
    mgemm_kernel<64, 128, 2, 0><<<GB, 256, 0, stream>>>(B1lo, (const bf16x8*)P_in, b_in, nullptr, nullptr, CcLo, 128, N);
    // 3. ph = P(h) -> Db [128]
    bprop_kernel<128><<<PG, 256, 0, stream>>>(CcLo, Db, row_start, csr, dinv, N);
    // 4. mu1 = relu(ph@w_mu0 + b) -> B1 [128] (px dead)
    mgemm_kernel<128, 128, 2, 0><<<GB, 256, 0, stream>>>(Db, (const bf16x8*)P_mu0, b_mu0, nullptr, nullptr, B1, 128, N);
    // 5. tmu = mu1@w_mu -> T cols 0..63 (CcHi, stride 128)
    mgemm_kernel<128, 64, 0, 0><<<GB, 256, 0, stream>>>(B1, (const bf16x8*)P_mu, nullptr, nullptr, nullptr, CcHi, 128, N);
    // 6. si1 = relu(ph@w_si0 + b) -> CcLo [128] (h dead)
    mgemm_kernel<128, 128, 2, 0><<<GB, 256, 0, stream>>>(Db, (const bf16x8*)P_si0, b_si0, nullptr, nullptr, CcLo, 128, N);
    // 7. tsi = si1@w_si -> T cols 64..127
    mgemm_kernel<128, 64, 0, 0><<<GB, 256, 0, stream>>>(CcLo, (const bf16x8*)P_si, nullptr, nullptr, nullptr, CcHi + 64, 128, N);
    // 8. mssz: prop T -> mu (M f32), si (S f32), z -> B1lo bf16 (mu1/ph dead)
    mssz_kernel<<<PG, 256, 0, stream>>>(CcHi, row_start, csr, dinv, b_mu, b_si, eps, M, S, B1lo, N);
    // 9. pz = P(z) -> B1hi [64]
    bprop_kernel<64><<<PG, 256, 0, stream>>>(B1lo, B1hi, row_start, csr, dinv, N);
    // 10. ppz = P(pz) -> xb region (x dead)
    bprop_kernel<64><<<PG, 256, 0, stream>>>(B1hi, xb, row_start, csr, dinv, N);
    // 11. r2 = relu(ppz@Wc + cvec*bzw + b_d0) -> CcLo [128] (si1 dead)
    mgemm_kernel<64, 128, 3, 0><<<GB, 256, 0, stream>>>(xb, (const bf16x8*)P_wc, bzw, b_d0, cvec, CcLo, 128, N);
    // 12. pr2 = P(r2) -> B1 [128] (z/pz dead)
    bprop_kernel<128><<<PG, 256, 0, stream>>>(CcLo, B1, row_start, csr, dinv, N);
    // 13. logits = pr2@w_out + b_out -> Cc f32 (final; reads B1 only)
    mgemm_kernel<128, 128, 1, 1><<<GB, 256, 0, stream>>>(B1, (const bf16x8*)P_out, b_out, nullptr, nullptr, Cc, 128, N);
}

// Round 8
// 660.069 us; speedup vs baseline: 1.2258x; 1.0205x over previous
//
#include <hip/hip_runtime.h>

// VGAE: 8 GCN layers, N=100000, E=1.6M, dims 64/128 — bf16 + MFMA.
// GCN(x,W,b) = P(x)@W + b, P(y) = Adjn@y + dinv^2*y (linear, commutes with W).
// Props: wave-per-node random gathers (~4TB/s demand ceiling — fabric-bound).
// Encoder 4 GEMMs fused into one kernel (ph read once, mu1/si1 stay in LDS).
// Binned CSR build; decoder 1-2 fused via Wc = w_z@w_d0.

typedef short bf16x8 __attribute__((ext_vector_type(8)));
typedef float f32x4 __attribute__((ext_vector_type(4)));

__device__ __forceinline__ ushort f2bf(float f) {           // RNE
    uint x = __float_as_uint(f);
    uint r = x + 0x7FFFu + ((x >> 16) & 1u);
    return (ushort)(r >> 16);
}
__device__ __forceinline__ float bf2f(ushort h) {
    return __uint_as_float(((uint)h) << 16);
}
__device__ __forceinline__ float dot2bf(uint a, uint b, float c) {
    float d;
    asm("v_dot2_f32_bf16 %0, %1, %2, %3" : "=v"(d) : "v"(a), "v"(b), "v"(c));
    return d;
}

// ------------------------------------------------------------------ counts: deg + binned histogram
__global__ __launch_bounds__(1024) void counts_kernel(const int* __restrict__ dst,
        int* __restrict__ deg, int* __restrict__ bc0, int E, int NB, int shift) {
    __shared__ int h[8192];
    for (int j = threadIdx.x; j < NB; j += 1024) h[j] = 0;
    __syncthreads();
    int stride = gridDim.x * 1024;
    for (int i = blockIdx.x * 1024 + threadIdx.x; i < E; i += stride) {
        int d = dst[i];
        atomicAdd(&deg[d], 1);
        atomicAdd(&h[d >> shift], 1);
    }
    __syncthreads();
    for (int j = threadIdx.x; j < NB; j += 1024) {
        int v = h[j];
        if (v) atomicAdd(&bc0[j], v);
    }
}

__global__ void dinv_kernel(const int* __restrict__ deg, float* __restrict__ dinv, int N) {
    int i = blockIdx.x * blockDim.x + threadIdx.x;
    if (i < N) dinv[i] = rsqrtf((float)(deg[i] + 1));
}

// ------------------------------------------------------------------ scan
__global__ __launch_bounds__(1024) void scan_block_kernel(const int* __restrict__ in,
                                                          int* __restrict__ out,
                                                          int* __restrict__ bsum, int n) {
    __shared__ int s[1024];
    int i = blockIdx.x * 1024 + threadIdx.x;
    int v = (i < n) ? in[i] : 0;
    s[threadIdx.x] = v;
    __syncthreads();
    for (int off = 1; off < 1024; off <<= 1) {
        int t = (threadIdx.x >= off) ? s[threadIdx.x - off] : 0;
        __syncthreads();
        s[threadIdx.x] += t;
        __syncthreads();
    }
    if (i < n) out[i] = s[threadIdx.x] - v;
    if (threadIdx.x == 1023) bsum[blockIdx.x] = s[1023];
}

__global__ __launch_bounds__(1024) void scan_partials_kernel(int* __restrict__ bsum, int nb) {
    __shared__ int s[1024];
    int v = (threadIdx.x < nb) ? bsum[threadIdx.x] : 0;
    s[threadIdx.x] = v;
    __syncthreads();
    for (int off = 1; off < 1024; off <<= 1) {
        int t = (threadIdx.x >= off) ? s[threadIdx.x - off] : 0;
        __syncthreads();
        s[threadIdx.x] += t;
        __syncthreads();
    }
    if (threadIdx.x < nb) bsum[threadIdx.x] = s[threadIdx.x] - v;
}

__global__ __launch_bounds__(1024) void scan_add_kernel(int* __restrict__ arr,
                                                        const int* __restrict__ bsum, int n, int total) {
    int i = blockIdx.x * 1024 + threadIdx.x;
    if (i < n) arr[i] += bsum[blockIdx.x];
    if (i == 0) arr[n] = total;
}

// ------------------------------------------------------------------ bin scatter + place
__global__ void scatter_kernel(const int* __restrict__ src, const int* __restrict__ dst,
                               const int* __restrict__ bin_start, int* __restrict__ bc1,
                               int2* __restrict__ ebuf, int E, int shift) {
    int i = blockIdx.x * blockDim.x + threadIdx.x;
    if (i < E) {
        int d = dst[i];
        int b = d >> shift;
        int pos = bin_start[b] + atomicAdd(&bc1[b], 1);
        ebuf[pos] = make_int2(src[i], d);
    }
}

// csr entry: {src, bf16(weight) in low 16 bits}
__global__ void place2_kernel(const int2* __restrict__ ebuf, const int* __restrict__ row_start,
                              int* __restrict__ cnt, int2* __restrict__ csr,
                              const float* __restrict__ dinv, int E) {
    int i = blockIdx.x * blockDim.x + threadIdx.x;
    if (i < E) {
        int2 e = ebuf[i];
        int pos = row_start[e.y] + atomicAdd(&cnt[e.y], 1);
        csr[pos] = make_int2(e.x, (int)(uint)f2bf(dinv[e.x] * dinv[e.y]));
    }
}

// ------------------------------------------------------------------ cvec[j] = dinv_j^2 + sum_w (bf16 weights, consistent with props)
__global__ void rowsum_kernel(const int2* __restrict__ csr, const int* __restrict__ row_start,
                              const float* __restrict__ dinv, float* __restrict__ cvec, int N) {
    int j = blockIdx.x * blockDim.x + threadIdx.x;
    if (j >= N) return;
    float s = dinv[j] * dinv[j];
    int b = row_start[j], e = row_start[j + 1];
    for (int k = b; k < e; ++k) s += bf2f((ushort)((uint)csr[k].y & 0xFFFFu));
    cvec[j] = s;
}

// ------------------------------------------------------------------ Wc = w_z@w_d0 packed bf16, bzw = b_z@w_d0
__global__ void wcpack_kernel(const float* __restrict__ w_z, const float* __restrict__ b_z,
                              const float* __restrict__ w_d0,
                              ushort* __restrict__ P_wc, float* __restrict__ bzw) {
    int o = blockIdx.x * 256 + threadIdx.x;
    if (o >= 65 * 128) return;
    int i = o >> 7, j = o & 127;
    float s = 0.f;
    for (int k = 0; k < 128; ++k) {
        float a = (i < 64) ? w_z[i * 128 + k] : b_z[k];
        s = fmaf(a, w_d0[k * 128 + j], s);
    }
    if (i < 64) {
        int c = j >> 4, kb = i >> 5, l = ((i >> 3) & 3) * 16 + (j & 15), e = i & 7;
        P_wc[(size_t)((c * 2 + kb) * 64 + l) * 8 + e] = f2bf(s);
    } else bzw[j] = s;
}

// ------------------------------------------------------------------ weight packs (6 weights, 1 launch)
__device__ __forceinline__ void pack_one(const float* __restrict__ W, ushort* __restrict__ P,
                                         int KI, int KO, int idx) {
    if (idx >= KI * KO) return;
    int e = idx & 7, l = (idx >> 3) & 63, t = idx >> 9;
    int KB = KI / 32;
    int c = t / KB, kb = t % KB;
    int k = kb * 32 + ((l >> 4) << 3) + e, col = c * 16 + (l & 15);
    P[idx] = f2bf(W[(size_t)k * KO + col]);
}

__global__ void megapack_kernel(const float* w_in, const float* w_mu0, const float* w_si0,
                                const float* w_mu, const float* w_si, const float* w_out,
                                ushort* P_in, ushort* P_mu0, ushort* P_si0,
                                ushort* P_mu, ushort* P_si, ushort* P_out) {
    int b = blockIdx.x, tid = threadIdx.x;
    if (b < 32)       pack_one(w_in,  P_in,  64, 128,  (b - 0)   * 256 + tid);
    else if (b < 96)  pack_one(w_mu0, P_mu0, 128, 128, (b - 32)  * 256 + tid);
    else if (b < 160) pack_one(w_si0, P_si0, 128, 128, (b - 96)  * 256 + tid);
    else if (b < 192) pack_one(w_mu,  P_mu,  128, 64,  (b - 160) * 256 + tid);
    else if (b < 224) pack_one(w_si,  P_si,  128, 64,  (b - 192) * 256 + tid);
    else              pack_one(w_out, P_out, 128, 128, (b - 224) * 256 + tid);
}

// ------------------------------------------------------------------ f32 -> bf16
__global__ void cvt8_kernel(const float* __restrict__ in, ushort* __restrict__ out, int n8) {
    int i = blockIdx.x * 256 + threadIdx.x;
    if (i >= n8) return;
    float4 a = ((const float4*)in)[i * 2];
    float4 b = ((const float4*)in)[i * 2 + 1];
    bf16x8 o;
    o[0] = (short)f2bf(a.x); o[1] = (short)f2bf(a.y);
    o[2] = (short)f2bf(a.z); o[3] = (short)f2bf(a.w);
    o[4] = (short)f2bf(b.x); o[5] = (short)f2bf(b.y);
    o[6] = (short)f2bf(b.z); o[7] = (short)f2bf(b.w);
    ((bf16x8*)out)[i] = o;
}

// ------------------------------------------------------------------ gather core: DEPTH edge-pairs per sub-slot per iter.
// All row loads independent -> 2*DEPTH loads in flight per wave.
template <int W, int DEPTH>
__device__ __forceinline__ void gather_pairs(float* acc, const ushort* __restrict__ xb,
        const int2* __restrict__ csr, int node, int beg, int end, int sub, int f8) {
    constexpr int SLOTS = 64 / (W / 8);
    for (int base = beg; base < end; base += 2 * SLOTS * DEPTH) {
        int sidx[DEPTH][2];
        uint wv[DEPTH][2];
        #pragma unroll
        for (int d = 0; d < DEPTH; ++d) {
            int e0 = base + 2 * (sub + SLOTS * d), e1 = e0 + 1;
            int2 p0 = csr[e0 < end ? e0 : beg];
            int2 p1 = csr[e1 < end ? e1 : beg];
            sidx[d][0] = (e0 < end) ? p0.x : node;
            sidx[d][1] = (e1 < end) ? p1.x : node;
            wv[d][0] = (e0 < end) ? (uint)p0.y : 0u;
            wv[d][1] = (e1 < end) ? (uint)p1.y : 0u;
        }
        uint4 rv[DEPTH][2];
        #pragma unroll
        for (int d = 0; d < DEPTH; ++d) {
            rv[d][0] = *(const uint4*)(xb + (size_t)sidx[d][0] * W + f8 * 8);
            rv[d][1] = *(const uint4*)(xb + (size_t)sidx[d][1] * W + f8 * 8);
        }
        #pragma unroll
        for (int d = 0; d < DEPTH; ++d) {
            uint wpk = __builtin_amdgcn_perm(wv[d][1], wv[d][0], 0x05040100u);
            uint4 v0 = rv[d][0], v1 = rv[d][1];
            uint t;
            t = __builtin_amdgcn_perm(v1.x, v0.x, 0x05040100u); acc[0] = dot2bf(t, wpk, acc[0]);
            t = __builtin_amdgcn_perm(v1.x, v0.x, 0x07060302u); acc[1] = dot2bf(t, wpk, acc[1]);
            t = __builtin_amdgcn_perm(v1.y, v0.y, 0x05040100u); acc[2] = dot2bf(t, wpk, acc[2]);
            t = __builtin_amdgcn_perm(v1.y, v0.y, 0x07060302u); acc[3] = dot2bf(t, wpk, acc[3]);
            t = __builtin_amdgcn_perm(v1.z, v0.z, 0x05040100u); acc[4] = dot2bf(t, wpk, acc[4]);
            t = __builtin_amdgcn_perm(v1.z, v0.z, 0x07060302u); acc[5] = dot2bf(t, wpk, acc[5]);
            t = __builtin_amdgcn_perm(v1.w, v0.w, 0x05040100u); acc[6] = dot2bf(t, wpk, acc[6]);
            t = __builtin_amdgcn_perm(v1.w, v0.w, 0x07060302u); acc[7] = dot2bf(t, wpk, acc[7]);
        }
    }
}

// ------------------------------------------------------------------ bf16 prop: out = Adjn@x + dinv^2*x (wave per node)
template <int W, int DEPTH>
__global__ __launch_bounds__(256) void bprop_kernel(const ushort* __restrict__ xb,
        ushort* __restrict__ out, const int* __restrict__ row_start,
        const int2* __restrict__ csr, const float* __restrict__ dinv, int N) {
    constexpr int L = W / 8;
    int wave = threadIdx.x >> 6, lane = threadIdx.x & 63;
    int node = blockIdx.x * 4 + wave;
    if (node >= N) return;
    int sub = lane / L, f8 = lane % L;
    int beg = row_start[node], end = row_start[node + 1];
    float d2 = dinv[node]; d2 *= d2;
    float acc[8] = {};
    gather_pairs<W, DEPTH>(acc, xb, csr, node, beg, end, sub, f8);
    #pragma unroll
    for (int m = L; m < 64; m <<= 1) {
        #pragma unroll
        for (int q = 0; q < 8; ++q) acc[q] += __shfl_xor(acc[q], m);
    }
    if (sub != 0) return;
    bf16x8 sv = *(const bf16x8*)(xb + (size_t)node * W + f8 * 8);
    bf16x8 oz;
    #pragma unroll
    for (int q = 0; q < 8; ++q) oz[q] = (short)f2bf(fmaf(d2, bf2f((ushort)sv[q]), acc[q]));
    *(bf16x8*)(out + (size_t)node * W + f8 * 8) = oz;
}

// ------------------------------------------------------------------ mssz: 128-prop of T=[tmu|tsi] -> mu, si, z
__global__ __launch_bounds__(256) void mssz_kernel(const ushort* __restrict__ T,
        const int* __restrict__ row_start, const int2* __restrict__ csr,
        const float* __restrict__ dinv, const float* __restrict__ b_mu,
        const float* __restrict__ b_si, const float* __restrict__ eps,
        float* __restrict__ M, float* __restrict__ S, ushort* __restrict__ zb, int N) {
    constexpr int L = 16;
    int wave = threadIdx.x >> 6, lane = threadIdx.x & 63;
    int node = blockIdx.x * 4 + wave;
    if (node >= N) return;
    int sub = lane / L, f8 = lane % L;
    int beg = row_start[node], end = row_start[node + 1];
    float d2 = dinv[node]; d2 *= d2;
    float acc[8] = {};
    gather_pairs<128, 2>(acc, T, csr, node, beg, end, sub, f8);
    #pragma unroll
    for (int m = 16; m < 64; m <<= 1) {
        #pragma unroll
        for (int q = 0; q < 8; ++q) acc[q] += __shfl_xor(acc[q], m);
    }
    if (sub != 0) return;
    bf16x8 sv = *(const bf16x8*)(T + (size_t)node * 128 + f8 * 8);
    #pragma unroll
    for (int q = 0; q < 8; ++q) acc[q] = fmaf(d2, bf2f((ushort)sv[q]), acc[q]);

    bool is_mu = (f8 < 8);
    const float* bp = is_mu ? b_mu : b_si;
    int o = (f8 & 7) * 8;
    float val[8];
    #pragma unroll
    for (int q = 0; q < 8; ++q) {
        float t = acc[q] + bp[o + q];
        val[q] = is_mu ? fmaxf(t, 0.f) : 1.f / (1.f + __expf(-t));
    }
    if (is_mu) {
        *(float4*)&M[(size_t)node * 64 + o]     = make_float4(val[0], val[1], val[2], val[3]);
        *(float4*)&M[(size_t)node * 64 + o + 4] = make_float4(val[4], val[5], val[6], val[7]);
    } else {
        *(float4*)&S[(size_t)node * 64 + o]     = make_float4(val[0], val[1], val[2], val[3]);
        *(float4*)&S[(size_t)node * 64 + o + 4] = make_float4(val[4], val[5], val[6], val[7]);
    }
    float oth[8];
    #pragma unroll
    for (int q = 0; q < 8; ++q) oth[q] = __shfl_xor(val[q], 8);
    if (is_mu) {   // lane holds mu (val) + si (oth): z = mu + si*eps
        float4 e0v = *(const float4*)&eps[(size_t)node * 64 + o];
        float4 e1v = *(const float4*)&eps[(size_t)node * 64 + o + 4];
        float ev[8] = {e0v.x, e0v.y, e0v.z, e0v.w, e1v.x, e1v.y, e1v.z, e1v.w};
        bf16x8 z;
        #pragma unroll
        for (int q = 0; q < 8; ++q) z[q] = (short)f2bf(fmaf(oth[q], ev[q], val[q]));
        *(bf16x8*)(zb + (size_t)node * 64 + o) = z;
    }
}

// ------------------------------------------------------------------ fused encoder GEMM chain:
// reads PH once -> mu1=relu(ph@w_mu0+b) (LDS) -> tmu=mu1@w_mu (regs)
//               -> si1=relu(ph@w_si0+b) (LDS) -> tsi=si1@w_si (regs) -> T=[tmu|tsi]
__global__ __launch_bounds__(256) void encgemm_kernel(const ushort* __restrict__ PH,
        const bf16x8* __restrict__ Pmu0, const float* __restrict__ b_mu0,
        const bf16x8* __restrict__ Pmu,
        const bf16x8* __restrict__ Psi0, const float* __restrict__ b_si0,
        const bf16x8* __restrict__ Psi,
        ushort* __restrict__ T, int N) {
    constexpr int STR = 136;                      // ushorts; 272B row stride (16B aligned)
    __shared__ __align__(16) ushort Ls[64 * STR];
    int w = threadIdx.x >> 6, l = threadIdx.x & 63;
    int lr = l & 15, lk = l >> 4;
    int rowbase = blockIdx.x * 64;
    int arow = rowbase + w * 16 + lr; if (arow > N - 1) arow = N - 1;

    bf16x8 aph[4];
    const ushort* pp = PH + (size_t)arow * 128 + lk * 8;
    #pragma unroll
    for (int kb = 0; kb < 4; ++kb) aph[kb] = *(const bf16x8*)(pp + kb * 32);

    int crow0 = w * 16 + lk * 4;                   // C-frag local rows
    int afrow = w * 16 + lr;                       // A-frag local row

    // ---- mu1 = relu(ph@w_mu0 + b) -> LDS
    #pragma unroll
    for (int c = 0; c < 8; ++c) {
        f32x4 acc = {0.f, 0.f, 0.f, 0.f};
        #pragma unroll
        for (int kb = 0; kb < 4; ++kb)
            acc = __builtin_amdgcn_mfma_f32_16x16x32_bf16(aph[kb], Pmu0[((size_t)c * 4 + kb) * 64 + l], acc, 0, 0, 0);
        float bv = b_mu0[c * 16 + lr];
        #pragma unroll
        for (int r = 0; r < 4; ++r)
            Ls[(crow0 + r) * STR + c * 16 + lr] = f2bf(fmaxf(acc[r] + bv, 0.f));
    }
    __syncthreads();
    // ---- tmu = mu1@w_mu
    bf16x8 am[4];
    #pragma unroll
    for (int kb = 0; kb < 4; ++kb) am[kb] = *(const bf16x8*)&Ls[afrow * STR + kb * 32 + lk * 8];
    f32x4 tmu[4];
    #pragma unroll
    for (int c = 0; c < 4; ++c) {
        f32x4 acc = {0.f, 0.f, 0.f, 0.f};
        #pragma unroll
        for (int kb = 0; kb < 4; ++kb)
            acc = __builtin_amdgcn_mfma_f32_16x16x32_bf16(am[kb], Pmu[((size_t)c * 4 + kb) * 64 + l], acc, 0, 0, 0);
        tmu[c] = acc;
    }
    __syncthreads();
    // ---- si1 = relu(ph@w_si0 + b) -> LDS
    #pragma unroll
    for (int c = 0; c < 8; ++c) {
        f32x4 acc = {0.f, 0.f, 0.f, 0.f};
        #pragma unroll
        for (int kb = 0; kb < 4; ++kb)
            acc = __builtin_amdgcn_mfma_f32_16x16x32_bf16(aph[kb], Psi0[((size_t)c * 4 + kb) * 64 + l], acc, 0, 0, 0);
        float bv = b_si0[c * 16 + lr];
        #pragma unroll
        for (int r = 0; r < 4; ++r)
            Ls[(crow0 + r) * STR + c * 16 + lr] = f2bf(fmaxf(acc[r] + bv, 0.f));
    }
    __syncthreads();
    // ---- tsi = si1@w_si
    #pragma unroll
    for (int kb = 0; kb < 4; ++kb) am[kb] = *(const bf16x8*)&Ls[afrow * STR + kb * 32 + lk * 8];
    f32x4 tsi[4];
    #pragma unroll
    for (int c = 0; c < 4; ++c) {
        f32x4 acc = {0.f, 0.f, 0.f, 0.f};
        #pragma unroll
        for (int kb = 0; kb < 4; ++kb)
            acc = __builtin_amdgcn_mfma_f32_16x16x32_bf16(am[kb], Psi[((size_t)c * 4 + kb) * 64 + l], acc, 0, 0, 0);
        tsi[c] = acc;
    }
    __syncthreads();
    // ---- stage T = [tmu | tsi] in LDS
    #pragma unroll
    for (int c = 0; c < 4; ++c) {
        #pragma unroll
        for (int r = 0; r < 4; ++r) {
            Ls[(crow0 + r) * STR + c * 16 + lr]      = f2bf(tmu[c][r]);
            Ls[(crow0 + r) * STR + 64 + c * 16 + lr] = f2bf(tsi[c][r]);
        }
    }
    __syncthreads();
    // ---- flush 64x128 bf16 coalesced
    for (int idx = threadIdx.x; idx < 64 * 16; idx += 256) {
        int row = idx >> 4, c8 = idx & 15;
        if (rowbase + row < N) {
            bf16x8 vv = *(const bf16x8*)&Ls[row * STR + c8 * 8];
            *(bf16x8*)(T + (size_t)(rowbase + row) * 128 + c8 * 8) = vv;
        }
    }
}

// ------------------------------------------------------------------ MFMA GEMM: out[N,·] = Xb[N,KI]@W + epilogue
// EPI: 0 none, 1 +bias, 2 +bias,relu, 3 relu(v + cvec[row]*bias + bias2).
// OUT: 0 bf16, 1 f32. Output staged via LDS for coalesced stores.
template <int KI, int KO, int EPI, int OUT>
__global__ __launch_bounds__(256) void mgemm_kernel(const ushort* __restrict__ Xb,
                                                    const bf16x8* __restrict__ Wp,
                                                    const float* __restrict__ bias,
                                                    const float* __restrict__ bias2,
                                                    const float* __restrict__ cvec,
                                                    void* __restrict__ outp, int ostride, int N) {
    constexpr int KB = KI / 32;
    constexpr int CT = KO / 16;
    constexpr size_t LSB = (OUT == 1) ? (size_t)64 * KO * 4 : (size_t)64 * KO * 2;
    __shared__ __align__(16) char LsRaw[LSB];

    int w = threadIdx.x >> 6, l = threadIdx.x & 63;
    int lr = l & 15, lk = l >> 4;
    int rowbase = blockIdx.x * 64;
    int r0 = rowbase + w * 16;

    int arow = r0 + lr; if (arow > N - 1) arow = N - 1;
    bf16x8 a[KB];
    const ushort* xp = Xb + (size_t)arow * KI + lk * 8;
    #pragma unroll
    for (int kb = 0; kb < KB; ++kb) a[kb] = *(const bf16x8*)(xp + kb * 32);

    float cv[4];
    if constexpr (EPI == 3) {
        #pragma unroll
        for (int r = 0; r < 4; ++r) {
            int rr = r0 + lk * 4 + r;
            cv[r] = cvec[rr < N ? rr : 0];
        }
    }

    #pragma unroll
    for (int c = 0; c < CT; ++c) {
        f32x4 acc = {0.f, 0.f, 0.f, 0.f};
        #pragma unroll
        for (int kb = 0; kb < KB; ++kb)
            acc = __builtin_amdgcn_mfma_f32_16x16x32_bf16(a[kb], Wp[((size_t)c * KB + kb) * 64 + l], acc, 0, 0, 0);
        int col = c * 16 + lr;
        float bv = 0.f, b2v = 0.f;
        if constexpr (EPI >= 1) bv = bias[col];
        if constexpr (EPI == 3) b2v = bias2[col];
        #pragma unroll
        for (int r = 0; r < 4; ++r) {
            float v = acc[r];
            if constexpr (EPI == 1) v += bv;
            if constexpr (EPI == 2) v = fmaxf(v + bv, 0.f);
            if constexpr (EPI == 3) v = fmaxf(v + cv[r] * bv + b2v, 0.f);
            int rl = w * 16 + lk * 4 + r;
            if constexpr (OUT == 0) ((ushort*)LsRaw)[(size_t)rl * KO + col] = f2bf(v);
            else                    ((float*)LsRaw)[(size_t)rl * KO + col] = v;
        }
    }
    __syncthreads();

    if constexpr (OUT == 0) {
        ushort* o = (ushort*)outp;
        constexpr int CH = 64 * KO / 8;
        for (int idx = threadIdx.x; idx < CH; idx += 256) {
            int row = idx / (KO / 8), c8 = idx % (KO / 8);
            if (rowbase + row < N)
                *(bf16x8*)(o + (size_t)(rowbase + row) * ostride + c8 * 8) = ((const bf16x8*)LsRaw)[idx];
        }
    } else {
        float* o = (float*)outp;
        constexpr int CH = 64 * KO / 4;
        for (int idx = threadIdx.x; idx < CH; idx += 256) {
            int row = idx / (KO / 4), c4 = idx % (KO / 4);
            if (rowbase + row < N)
                *(float4*)(o + (size_t)(rowbase + row) * ostride + c4 * 4) = ((const float4*)LsRaw)[idx];
        }
    }
}

// ------------------------------------------------------------------ launch
extern "C" void kernel_launch(void* const* d_in, const int* in_sizes, int n_in,
                              void* d_out, int out_size, void* d_ws, size_t ws_size,
                              hipStream_t stream) {
    const float* x    = (const float*)d_in[0];
    const float* eps  = (const float*)d_in[1];
    const int*   ei   = (const int*)d_in[2];
    const float* w_in  = (const float*)d_in[3];  const float* b_in  = (const float*)d_in[4];
    const float* w_mu0 = (const float*)d_in[5];  const float* b_mu0 = (const float*)d_in[6];
    const float* w_mu  = (const float*)d_in[7];  const float* b_mu  = (const float*)d_in[8];
    const float* w_si0 = (const float*)d_in[9];  const float* b_si0 = (const float*)d_in[10];
    const float* w_si  = (const float*)d_in[11]; const float* b_si  = (const float*)d_in[12];
    const float* w_z   = (const float*)d_in[13]; const float* b_z   = (const float*)d_in[14];
    const float* w_d0  = (const float*)d_in[15]; const float* b_d0  = (const float*)d_in[16];
    const float* w_out = (const float*)d_in[17]; const float* b_out = (const float*)d_in[18];

    const int N = in_sizes[0] / 64;
    const int E = in_sizes[2] / 2;
    const int* srcI = ei;
    const int* dstI = ei + E;

    int shift = 4;
    while (((N >> shift) + 1) > 8192) shift++;
    const int NB = (N >> shift) + 1;

    auto align = [](size_t v) { return (v + 255) & ~(size_t)255; };
    char* wsp = (char*)d_ws;
    size_t off = 0;
    int*    deg       = (int*)(wsp + off);    size_t deg_off = off; off = align(off + (size_t)N * 4);
    int*    bc0       = (int*)(wsp + off);    off = align(off + (size_t)NB * 4);
    int*    bc1       = (int*)(wsp + off);    off = align(off + (size_t)NB * 4);
    size_t  zero_span = off - deg_off;
    float*  cvec      = (float*)(wsp + off);  off = align(off + (size_t)N * 4);
    int*    row_start = (int*)(wsp + off);    off = align(off + (size_t)(N + 1) * 4);
    int*    bin_start = (int*)(wsp + off);    off = align(off + (size_t)(NB + 1) * 4);
    int*    bsum      = (int*)(wsp + off);    off = align(off + 1024 * 4);
    float*  dinv      = (float*)(wsp + off);  off = align(off + (size_t)N * 4);
    float*  bzw       = (float*)(wsp + off);  off = align(off + 128 * 4);
    ushort* P_in      = (ushort*)(wsp + off); off = align(off + 64 * 128 * 2);
    ushort* P_mu0     = (ushort*)(wsp + off); off = align(off + 128 * 128 * 2);
    ushort* P_si0     = (ushort*)(wsp + off); off = align(off + 128 * 128 * 2);
    ushort* P_mu      = (ushort*)(wsp + off); off = align(off + 128 * 64 * 2);
    ushort* P_si      = (ushort*)(wsp + off); off = align(off + 128 * 64 * 2);
    ushort* P_wc      = (ushort*)(wsp + off); off = align(off + 64 * 128 * 2);
    ushort* P_out     = (ushort*)(wsp + off); off = align(off + 128 * 128 * 2);
    int2*   csr       = (int2*)(wsp + off);   off = align(off + (size_t)E * 8);
    int2*   ebuf      = (int2*)(wsp + off);   off = align(off + (size_t)E * 8);  // alias: xb after place2
    ushort* xb        = (ushort*)ebuf;        // [N,64] bf16 x, later ppz
    ushort* B1        = (ushort*)(wsp + off); off = align(off + (size_t)N * 128 * 2);
    ushort* B1lo = B1;                        // [N,64]
    ushort* B1hi = B1 + (size_t)N * 64;       // [N,64]

    float* Cc = (float*)d_out;               // logits f32 [N,128] (final)
    float* M  = Cc + (size_t)N * 128;        // mu f32 (final)
    float* S  = M + (size_t)N * 64;          // si f32 (final)
    ushort* CcLo = (ushort*)Cc;              // bf16 [N,128] scratch: h, later r2
    ushort* CcHi = (ushort*)(Cc + (size_t)N * 64);  // bf16 [N,128] scratch: T=[tmu|tsi]
    ushort* Db   = (ushort*)M;               // bf16 [N,128] scratch: ph (dead before mssz writes M)

    const int TB = 256;
    hipMemsetAsync(deg, 0, zero_span, stream);
    counts_kernel<<<256, 1024, 0, stream>>>(dstI, deg, bc0, E, NB, shift);
    dinv_kernel<<<(N + TB - 1) / TB, TB, 0, stream>>>(deg, dinv, N);
    int nbN = (N + 1023) / 1024;
    scan_block_kernel<<<nbN, 1024, 0, stream>>>(deg, row_start, bsum, N);
    scan_partials_kernel<<<1, 1024, 0, stream>>>(bsum, nbN);
    scan_add_kernel<<<nbN, 1024, 0, stream>>>(row_start, bsum, N, E);
    int nbB = (NB + 1023) / 1024;
    scan_block_kernel<<<nbB, 1024, 0, stream>>>(bc0, bin_start, bsum, NB);
    scan_partials_kernel<<<1, 1024, 0, stream>>>(bsum, nbB);
    scan_add_kernel<<<nbB, 1024, 0, stream>>>(bin_start, bsum, NB, E);
    hipMemsetAsync(deg, 0, (size_t)N * 4, stream);   // deg reused as place counter
    scatter_kernel<<<(E + TB - 1) / TB, TB, 0, stream>>>(srcI, dstI, bin_start, bc1, ebuf, E, shift);
    place2_kernel<<<(E + TB - 1) / TB, TB, 0, stream>>>(ebuf, row_start, deg, csr, dinv, E);
    rowsum_kernel<<<(N + TB - 1) / TB, TB, 0, stream>>>(csr, row_start, dinv, cvec, N);
    wcpack_kernel<<<(65 * 128 + 255) / 256, 256, 0, stream>>>(w_z, b_z, w_d0, P_wc, bzw);
    megapack_kernel<<<288, 256, 0, stream>>>(w_in, w_mu0, w_si0, w_mu, w_si, w_out,
                                             P_in, P_mu0, P_si0, P_mu, P_si, P_out);
    cvt8_kernel<<<((N * 8) + 255) / 256, 256, 0, stream>>>(x, xb, N * 8);  // ebuf alias dead

    int PG = (N + 3) / 4;
    int GB = (N + 63) / 64;

    // 1. px = P(x) -> B1lo [64]
    bprop_kernel<64, 1><<<PG, 256, 0, stream>>>(xb, B1lo, row_start, csr, dinv, N);
    // 2. h = relu(px@w_in + b) -> CcLo [128]
    mgemm_kernel<64, 128, 2, 0><<<GB, 256, 0, stream>>>(B1lo, (const bf16x8*)P_in, b_in, nullptr, nullptr, CcLo, 128, N);
    // 3. ph = P(h) -> Db [128]
    bprop_kernel<128, 2><<<PG, 256, 0, stream>>>(CcLo, Db, row_start, csr, dinv, N);
    // 4. fused encoder GEMMs: ph -> T=[tmu|tsi] (CcHi); mu1/si1 never leave LDS
    encgemm_kernel<<<GB, 256, 0, stream>>>(Db,
                                           (const bf16x8*)P_mu0, b_mu0, (const bf16x8*)P_mu,
                                           (const bf16x8*)P_si0, b_si0, (const bf16x8*)P_si,
                                           CcHi, N);
    // 5. mssz: prop T -> mu (M f32), si (S f32), z -> B1lo bf16 (ph dead)
    mssz_kernel<<<PG, 256, 0, stream>>>(CcHi, row_start, csr, dinv, b_mu, b_si, eps, M, S, B1lo, N);
    // 6. pz = P(z) -> B1hi [64]
    bprop_kernel<64, 1><<<PG, 256, 0, stream>>>(B1lo, B1hi, row_start, csr, dinv, N);
    // 7. ppz = P(pz) -> xb region (x dead)
    bprop_kernel<64, 1><<<PG, 256, 0, stream>>>(B1hi, xb, row_start, csr, dinv, N);
    // 8. r2 = relu(ppz@Wc + cvec*bzw + b_d0) -> CcLo [128] (h dead)
    mgemm_kernel<64, 128, 3, 0><<<GB, 256, 0, stream>>>(xb, (const bf16x8*)P_wc, bzw, b_d0, cvec, CcLo, 128, N);
    // 9. pr2 = P(r2) -> B1 [128] (z/pz dead)
    bprop_kernel<128, 2><<<PG, 256, 0, stream>>>(CcLo, B1, row_start, csr, dinv, N);
    // 10. logits = pr2@w_out + b_out -> Cc f32 (final; reads B1 only)
    mgemm_kernel<128, 128, 1, 1><<<GB, 256, 0, stream>>>(B1, (const bf16x8*)P_out, b_out, nullptr, nullptr, Cc, 128, N);
}

// Round 9
// 654.294 us; speedup vs baseline: 1.2366x; 1.0088x over previous
//
#include <hip/hip_runtime.h>

// VGAE: 8 GCN layers, N=100000, E=1.6M, dims 64/128 — bf16 + MFMA.
// GCN(x,W,b) = P(x)@W + b, P(y) = Adjn@y + dinv^2*y (linear, commutes with W).
// Props: 2 nodes per wave, software-pipelined (desc/csr/self hoisted, cross-node
// overlap) — props are latency-CHAIN bound (~3 serial trips/node), not BW/VALU.
// Encoder 4 GEMMs fused (encgemm); binned CSR build; decoder 1-2 fused via Wc.

typedef short bf16x8 __attribute__((ext_vector_type(8)));
typedef float f32x4 __attribute__((ext_vector_type(4)));

__device__ __forceinline__ ushort f2bf(float f) {           // RNE
    uint x = __float_as_uint(f);
    uint r = x + 0x7FFFu + ((x >> 16) & 1u);
    return (ushort)(r >> 16);
}
__device__ __forceinline__ float bf2f(ushort h) {
    return __uint_as_float(((uint)h) << 16);
}
__device__ __forceinline__ float dot2bf(uint a, uint b, float c) {
    float d;
    asm("v_dot2_f32_bf16 %0, %1, %2, %3" : "=v"(d) : "v"(a), "v"(b), "v"(c));
    return d;
}

// ------------------------------------------------------------------ counts: deg + binned histogram
__global__ __launch_bounds__(1024) void counts_kernel(const int* __restrict__ dst,
        int* __restrict__ deg, int* __restrict__ bc0, int E, int NB, int shift) {
    __shared__ int h[8192];
    for (int j = threadIdx.x; j < NB; j += 1024) h[j] = 0;
    __syncthreads();
    int stride = gridDim.x * 1024;
    for (int i = blockIdx.x * 1024 + threadIdx.x; i < E; i += stride) {
        int d = dst[i];
        atomicAdd(&deg[d], 1);
        atomicAdd(&h[d >> shift], 1);
    }
    __syncthreads();
    for (int j = threadIdx.x; j < NB; j += 1024) {
        int v = h[j];
        if (v) atomicAdd(&bc0[j], v);
    }
}

__global__ void dinv_kernel(const int* __restrict__ deg, float* __restrict__ dinv, int N) {
    int i = blockIdx.x * blockDim.x + threadIdx.x;
    if (i < N) dinv[i] = rsqrtf((float)(deg[i] + 1));
}

// ------------------------------------------------------------------ scan
__global__ __launch_bounds__(1024) void scan_block_kernel(const int* __restrict__ in,
                                                          int* __restrict__ out,
                                                          int* __restrict__ bsum, int n) {
    __shared__ int s[1024];
    int i = blockIdx.x * 1024 + threadIdx.x;
    int v = (i < n) ? in[i] : 0;
    s[threadIdx.x] = v;
    __syncthreads();
    for (int off = 1; off < 1024; off <<= 1) {
        int t = (threadIdx.x >= off) ? s[threadIdx.x - off] : 0;
        __syncthreads();
        s[threadIdx.x] += t;
        __syncthreads();
    }
    if (i < n) out[i] = s[threadIdx.x] - v;
    if (threadIdx.x == 1023) bsum[blockIdx.x] = s[1023];
}

__global__ __launch_bounds__(1024) void scan_partials_kernel(int* __restrict__ bsum, int nb) {
    __shared__ int s[1024];
    int v = (threadIdx.x < nb) ? bsum[threadIdx.x] : 0;
    s[threadIdx.x] = v;
    __syncthreads();
    for (int off = 1; off < 1024; off <<= 1) {
        int t = (threadIdx.x >= off) ? s[threadIdx.x - off] : 0;
        __syncthreads();
        s[threadIdx.x] += t;
        __syncthreads();
    }
    if (threadIdx.x < nb) bsum[threadIdx.x] = s[threadIdx.x] - v;
}

__global__ __launch_bounds__(1024) void scan_add_kernel(int* __restrict__ arr,
                                                        const int* __restrict__ bsum, int n, int total) {
    int i = blockIdx.x * 1024 + threadIdx.x;
    if (i < n) arr[i] += bsum[blockIdx.x];
    if (i == 0) arr[n] = total;
}

// ------------------------------------------------------------------ bin scatter + place
__global__ void scatter_kernel(const int* __restrict__ src, const int* __restrict__ dst,
                               const int* __restrict__ bin_start, int* __restrict__ bc1,
                               int2* __restrict__ ebuf, int E, int shift) {
    int i = blockIdx.x * blockDim.x + threadIdx.x;
    if (i < E) {
        int d = dst[i];
        int b = d >> shift;
        int pos = bin_start[b] + atomicAdd(&bc1[b], 1);
        ebuf[pos] = make_int2(src[i], d);
    }
}

// csr entry: {src, bf16(weight) in low 16 bits}
__global__ void place2_kernel(const int2* __restrict__ ebuf, const int* __restrict__ row_start,
                              int* __restrict__ cnt, int2* __restrict__ csr,
                              const float* __restrict__ dinv, int E) {
    int i = blockIdx.x * blockDim.x + threadIdx.x;
    if (i < E) {
        int2 e = ebuf[i];
        int pos = row_start[e.y] + atomicAdd(&cnt[e.y], 1);
        csr[pos] = make_int2(e.x, (int)(uint)f2bf(dinv[e.x] * dinv[e.y]));
    }
}

// ------------------------------------------------------------------ cvec[j] = dinv_j^2 + sum_w
__global__ void rowsum_kernel(const int2* __restrict__ csr, const int* __restrict__ row_start,
                              const float* __restrict__ dinv, float* __restrict__ cvec, int N) {
    int j = blockIdx.x * blockDim.x + threadIdx.x;
    if (j >= N) return;
    float s = dinv[j] * dinv[j];
    int b = row_start[j], e = row_start[j + 1];
    for (int k = b; k < e; ++k) s += bf2f((ushort)((uint)csr[k].y & 0xFFFFu));
    cvec[j] = s;
}

// ------------------------------------------------------------------ Wc = w_z@w_d0 packed bf16, bzw = b_z@w_d0
__global__ void wcpack_kernel(const float* __restrict__ w_z, const float* __restrict__ b_z,
                              const float* __restrict__ w_d0,
                              ushort* __restrict__ P_wc, float* __restrict__ bzw) {
    int o = blockIdx.x * 256 + threadIdx.x;
    if (o >= 65 * 128) return;
    int i = o >> 7, j = o & 127;
    float s = 0.f;
    for (int k = 0; k < 128; ++k) {
        float a = (i < 64) ? w_z[i * 128 + k] : b_z[k];
        s = fmaf(a, w_d0[k * 128 + j], s);
    }
    if (i < 64) {
        int c = j >> 4, kb = i >> 5, l = ((i >> 3) & 3) * 16 + (j & 15), e = i & 7;
        P_wc[(size_t)((c * 2 + kb) * 64 + l) * 8 + e] = f2bf(s);
    } else bzw[j] = s;
}

// ------------------------------------------------------------------ weight packs (6 weights, 1 launch)
__device__ __forceinline__ void pack_one(const float* __restrict__ W, ushort* __restrict__ P,
                                         int KI, int KO, int idx) {
    if (idx >= KI * KO) return;
    int e = idx & 7, l = (idx >> 3) & 63, t = idx >> 9;
    int KB = KI / 32;
    int c = t / KB, kb = t % KB;
    int k = kb * 32 + ((l >> 4) << 3) + e, col = c * 16 + (l & 15);
    P[idx] = f2bf(W[(size_t)k * KO + col]);
}

__global__ void megapack_kernel(const float* w_in, const float* w_mu0, const float* w_si0,
                                const float* w_mu, const float* w_si, const float* w_out,
                                ushort* P_in, ushort* P_mu0, ushort* P_si0,
                                ushort* P_mu, ushort* P_si, ushort* P_out) {
    int b = blockIdx.x, tid = threadIdx.x;
    if (b < 32)       pack_one(w_in,  P_in,  64, 128,  (b - 0)   * 256 + tid);
    else if (b < 96)  pack_one(w_mu0, P_mu0, 128, 128, (b - 32)  * 256 + tid);
    else if (b < 160) pack_one(w_si0, P_si0, 128, 128, (b - 96)  * 256 + tid);
    else if (b < 192) pack_one(w_mu,  P_mu,  128, 64,  (b - 160) * 256 + tid);
    else if (b < 224) pack_one(w_si,  P_si,  128, 64,  (b - 192) * 256 + tid);
    else              pack_one(w_out, P_out, 128, 128, (b - 224) * 256 + tid);
}

// ------------------------------------------------------------------ f32 -> bf16
__global__ void cvt8_kernel(const float* __restrict__ in, ushort* __restrict__ out, int n8) {
    int i = blockIdx.x * 256 + threadIdx.x;
    if (i >= n8) return;
    float4 a = ((const float4*)in)[i * 2];
    float4 b = ((const float4*)in)[i * 2 + 1];
    bf16x8 o;
    o[0] = (short)f2bf(a.x); o[1] = (short)f2bf(a.y);
    o[2] = (short)f2bf(a.z); o[3] = (short)f2bf(a.w);
    o[4] = (short)f2bf(b.x); o[5] = (short)f2bf(b.y);
    o[6] = (short)f2bf(b.z); o[7] = (short)f2bf(b.w);
    ((bf16x8*)out)[i] = o;
}

// ================================================================== pipelined gather state
// 16 edges per iteration for both widths: W=64 -> 8 slots x 1 pair; W=128 -> 4 slots x 2 pairs.
template <int W>
struct GS {
    static constexpr int L = W / 8;
    static constexpr int SLOTS = 64 / L;
    static constexpr int PP = 16 / (2 * SLOTS);
    int2 c[2 * PP];
    uint4 r[2 * PP];
};

template <int W>
__device__ __forceinline__ void g_csr(GS<W>& st, const int2* __restrict__ csr,
                                      int base, int beg, int end, int sub) {
    int safe = (end > beg) ? beg : 0;
    #pragma unroll
    for (int p = 0; p < GS<W>::PP; ++p) {
        int e0 = base + 2 * (sub + GS<W>::SLOTS * p);
        st.c[2 * p]     = csr[e0 < end ? e0 : safe];
        st.c[2 * p + 1] = csr[e0 + 1 < end ? e0 + 1 : safe];
    }
}

template <int W>
__device__ __forceinline__ void g_rows(GS<W>& st, const ushort* __restrict__ xb, int f8) {
    #pragma unroll
    for (int i = 0; i < 2 * GS<W>::PP; ++i)
        st.r[i] = *(const uint4*)(xb + (size_t)st.c[i].x * W + f8 * 8);
}

template <int W>
__device__ __forceinline__ void g_consume(GS<W>& st, float* acc, int base, int end, int sub) {
    #pragma unroll
    for (int p = 0; p < GS<W>::PP; ++p) {
        int e0 = base + 2 * (sub + GS<W>::SLOTS * p);
        uint w0 = (e0 < end) ? (uint)st.c[2 * p].y : 0u;
        uint w1 = (e0 + 1 < end) ? (uint)st.c[2 * p + 1].y : 0u;
        uint wpk = __builtin_amdgcn_perm(w1, w0, 0x05040100u);   // (w0 lo16, w1 hi16)
        uint4 v0 = st.r[2 * p], v1 = st.r[2 * p + 1];
        uint t;
        t = __builtin_amdgcn_perm(v1.x, v0.x, 0x05040100u); acc[0] = dot2bf(t, wpk, acc[0]);
        t = __builtin_amdgcn_perm(v1.x, v0.x, 0x07060302u); acc[1] = dot2bf(t, wpk, acc[1]);
        t = __builtin_amdgcn_perm(v1.y, v0.y, 0x05040100u); acc[2] = dot2bf(t, wpk, acc[2]);
        t = __builtin_amdgcn_perm(v1.y, v0.y, 0x07060302u); acc[3] = dot2bf(t, wpk, acc[3]);
        t = __builtin_amdgcn_perm(v1.z, v0.z, 0x05040100u); acc[4] = dot2bf(t, wpk, acc[4]);
        t = __builtin_amdgcn_perm(v1.z, v0.z, 0x07060302u); acc[5] = dot2bf(t, wpk, acc[5]);
        t = __builtin_amdgcn_perm(v1.w, v0.w, 0x05040100u); acc[6] = dot2bf(t, wpk, acc[6]);
        t = __builtin_amdgcn_perm(v1.w, v0.w, 0x07060302u); acc[7] = dot2bf(t, wpk, acc[7]);
    }
}

// ------------------------------------------------------------------ pipelined prop: 2 nodes/wave, bf16 out
template <int W>
__global__ __launch_bounds__(256) void pprop_kernel(const ushort* __restrict__ xb,
        ushort* __restrict__ out, const int* __restrict__ row_start,
        const int2* __restrict__ csr, const float* __restrict__ dinv, int N) {
    constexpr int L = W / 8;
    int wave = threadIdx.x >> 6, lane = threadIdx.x & 63;
    int nb = (blockIdx.x * 4 + wave) * 2;
    if (nb >= N) return;
    int sub = lane / L, f8 = lane % L;
    bool v1 = (nb + 1) < N;
    int n0 = nb, n1 = v1 ? nb + 1 : nb;

    int2 rs01 = *(const int2*)&row_start[nb];
    int rs2 = row_start[v1 ? nb + 2 : nb + 1];
    int beg0 = rs01.x, end0 = rs01.y;
    int beg1 = rs01.y, end1 = v1 ? rs2 : rs01.y;

    float d20 = dinv[n0], d21 = dinv[n1];
    bf16x8 sv0 = *(const bf16x8*)(xb + (size_t)n0 * W + f8 * 8);
    bf16x8 sv1 = *(const bf16x8*)(xb + (size_t)n1 * W + f8 * 8);

    GS<W> sA, sB, sA2, sB2;
    g_csr(sA, csr, beg0, beg0, end0, sub);
    g_csr(sB, csr, beg1, beg1, end1, sub);
    g_csr(sA2, csr, beg0 + 16, beg0, end0, sub);
    g_csr(sB2, csr, beg1 + 16, beg1, end1, sub);
    g_rows(sA, xb, f8);
    g_rows(sB, xb, f8);

    float a0[8] = {}, a1[8] = {};
    bool m0 = (beg0 + 16) < end0, m1 = (beg1 + 16) < end1;
    g_consume(sA, a0, beg0, end0, sub);
    if (m0) g_rows(sA2, xb, f8);
    g_consume(sB, a1, beg1, end1, sub);
    if (m1) g_rows(sB2, xb, f8);
    if (m0) {
        g_consume(sA2, a0, beg0 + 16, end0, sub);
        for (int base = beg0 + 32; base < end0; base += 16) {
            GS<W> t;
            g_csr(t, csr, base, beg0, end0, sub);
            g_rows(t, xb, f8);
            g_consume(t, a0, base, end0, sub);
        }
    }
    if (m1) {
        g_consume(sB2, a1, beg1 + 16, end1, sub);
        for (int base = beg1 + 32; base < end1; base += 16) {
            GS<W> t;
            g_csr(t, csr, base, beg1, end1, sub);
            g_rows(t, xb, f8);
            g_consume(t, a1, base, end1, sub);
        }
    }

    #pragma unroll
    for (int m = L; m < 64; m <<= 1) {
        #pragma unroll
        for (int q = 0; q < 8; ++q) {
            a0[q] += __shfl_xor(a0[q], m);
            a1[q] += __shfl_xor(a1[q], m);
        }
    }
    if (sub == 0) {
        float d2 = d20 * d20;
        bf16x8 o0;
        #pragma unroll
        for (int q = 0; q < 8; ++q) o0[q] = (short)f2bf(fmaf(d2, bf2f((ushort)sv0[q]), a0[q]));
        *(bf16x8*)(out + (size_t)n0 * W + f8 * 8) = o0;
        if (v1) {
            float e2 = d21 * d21;
            bf16x8 o1;
            #pragma unroll
            for (int q = 0; q < 8; ++q) o1[q] = (short)f2bf(fmaf(e2, bf2f((ushort)sv1[q]), a1[q]));
            *(bf16x8*)(out + (size_t)n1 * W + f8 * 8) = o1;
        }
    }
}

// ------------------------------------------------------------------ pmssz: pipelined 128-prop of T -> mu, si, z
__device__ __forceinline__ void mssz_epi(const float* acc, int node, int f8,
        const float* __restrict__ b_mu, const float* __restrict__ b_si,
        const float* __restrict__ eps, float* __restrict__ M, float* __restrict__ S,
        ushort* __restrict__ zb) {
    bool is_mu = (f8 < 8);
    const float* bp = is_mu ? b_mu : b_si;
    int o = (f8 & 7) * 8;
    float val[8];
    #pragma unroll
    for (int q = 0; q < 8; ++q) {
        float t = acc[q] + bp[o + q];
        val[q] = is_mu ? fmaxf(t, 0.f) : 1.f / (1.f + __expf(-t));
    }
    if (is_mu) {
        *(float4*)&M[(size_t)node * 64 + o]     = make_float4(val[0], val[1], val[2], val[3]);
        *(float4*)&M[(size_t)node * 64 + o + 4] = make_float4(val[4], val[5], val[6], val[7]);
    } else {
        *(float4*)&S[(size_t)node * 64 + o]     = make_float4(val[0], val[1], val[2], val[3]);
        *(float4*)&S[(size_t)node * 64 + o + 4] = make_float4(val[4], val[5], val[6], val[7]);
    }
    float oth[8];
    #pragma unroll
    for (int q = 0; q < 8; ++q) oth[q] = __shfl_xor(val[q], 8);
    if (is_mu) {   // lane holds mu (val) + si (oth): z = mu + si*eps
        float4 e0v = *(const float4*)&eps[(size_t)node * 64 + o];
        float4 e1v = *(const float4*)&eps[(size_t)node * 64 + o + 4];
        float ev[8] = {e0v.x, e0v.y, e0v.z, e0v.w, e1v.x, e1v.y, e1v.z, e1v.w};
        bf16x8 z;
        #pragma unroll
        for (int q = 0; q < 8; ++q) z[q] = (short)f2bf(fmaf(oth[q], ev[q], val[q]));
        *(bf16x8*)(zb + (size_t)node * 64 + o) = z;
    }
}

__global__ __launch_bounds__(256) void pmssz_kernel(const ushort* __restrict__ T,
        const int* __restrict__ row_start, const int2* __restrict__ csr,
        const float* __restrict__ dinv, const float* __restrict__ b_mu,
        const float* __restrict__ b_si, const float* __restrict__ eps,
        float* __restrict__ M, float* __restrict__ S, ushort* __restrict__ zb, int N) {
    constexpr int W = 128, L = 16;
    int wave = threadIdx.x >> 6, lane = threadIdx.x & 63;
    int nb = (blockIdx.x * 4 + wave) * 2;
    if (nb >= N) return;
    int sub = lane / L, f8 = lane % L;
    bool v1 = (nb + 1) < N;
    int n0 = nb, n1 = v1 ? nb + 1 : nb;

    int2 rs01 = *(const int2*)&row_start[nb];
    int rs2 = row_start[v1 ? nb + 2 : nb + 1];
    int beg0 = rs01.x, end0 = rs01.y;
    int beg1 = rs01.y, end1 = v1 ? rs2 : rs01.y;

    float d20 = dinv[n0], d21 = dinv[n1];
    bf16x8 sv0 = *(const bf16x8*)(T + (size_t)n0 * W + f8 * 8);
    bf16x8 sv1 = *(const bf16x8*)(T + (size_t)n1 * W + f8 * 8);

    GS<W> sA, sB, sA2, sB2;
    g_csr(sA, csr, beg0, beg0, end0, sub);
    g_csr(sB, csr, beg1, beg1, end1, sub);
    g_csr(sA2, csr, beg0 + 16, beg0, end0, sub);
    g_csr(sB2, csr, beg1 + 16, beg1, end1, sub);
    g_rows(sA, T, f8);
    g_rows(sB, T, f8);

    float a0[8] = {}, a1[8] = {};
    bool m0 = (beg0 + 16) < end0, m1 = (beg1 + 16) < end1;
    g_consume(sA, a0, beg0, end0, sub);
    if (m0) g_rows(sA2, T, f8);
    g_consume(sB, a1, beg1, end1, sub);
    if (m1) g_rows(sB2, T, f8);
    if (m0) {
        g_consume(sA2, a0, beg0 + 16, end0, sub);
        for (int base = beg0 + 32; base < end0; base += 16) {
            GS<W> t;
            g_csr(t, csr, base, beg0, end0, sub);
            g_rows(t, T, f8);
            g_consume(t, a0, base, end0, sub);
        }
    }
    if (m1) {
        g_consume(sB2, a1, beg1 + 16, end1, sub);
        for (int base = beg1 + 32; base < end1; base += 16) {
            GS<W> t;
            g_csr(t, csr, base, beg1, end1, sub);
            g_rows(t, T, f8);
            g_consume(t, a1, base, end1, sub);
        }
    }

    #pragma unroll
    for (int m = L; m < 64; m <<= 1) {
        #pragma unroll
        for (int q = 0; q < 8; ++q) {
            a0[q] += __shfl_xor(a0[q], m);
            a1[q] += __shfl_xor(a1[q], m);
        }
    }
    if (sub == 0) {
        float d2 = d20 * d20;
        #pragma unroll
        for (int q = 0; q < 8; ++q) a0[q] = fmaf(d2, bf2f((ushort)sv0[q]), a0[q]);
        mssz_epi(a0, n0, f8, b_mu, b_si, eps, M, S, zb);
        if (v1) {
            float e2 = d21 * d21;
            #pragma unroll
            for (int q = 0; q < 8; ++q) a1[q] = fmaf(e2, bf2f((ushort)sv1[q]), a1[q]);
            mssz_epi(a1, n1, f8, b_mu, b_si, eps, M, S, zb);
        }
    }
}

// ------------------------------------------------------------------ fused encoder GEMM chain
__global__ __launch_bounds__(256) void encgemm_kernel(const ushort* __restrict__ PH,
        const bf16x8* __restrict__ Pmu0, const float* __restrict__ b_mu0,
        const bf16x8* __restrict__ Pmu,
        const bf16x8* __restrict__ Psi0, const float* __restrict__ b_si0,
        const bf16x8* __restrict__ Psi,
        ushort* __restrict__ T, int N) {
    constexpr int STR = 136;
    __shared__ __align__(16) ushort Ls[64 * STR];
    int w = threadIdx.x >> 6, l = threadIdx.x & 63;
    int lr = l & 15, lk = l >> 4;
    int rowbase = blockIdx.x * 64;
    int arow = rowbase + w * 16 + lr; if (arow > N - 1) arow = N - 1;

    bf16x8 aph[4];
    const ushort* pp = PH + (size_t)arow * 128 + lk * 8;
    #pragma unroll
    for (int kb = 0; kb < 4; ++kb) aph[kb] = *(const bf16x8*)(pp + kb * 32);

    int crow0 = w * 16 + lk * 4;
    int afrow = w * 16 + lr;

    #pragma unroll
    for (int c = 0; c < 8; ++c) {
        f32x4 acc = {0.f, 0.f, 0.f, 0.f};
        #pragma unroll
        for (int kb = 0; kb < 4; ++kb)
            acc = __builtin_amdgcn_mfma_f32_16x16x32_bf16(aph[kb], Pmu0[((size_t)c * 4 + kb) * 64 + l], acc, 0, 0, 0);
        float bv = b_mu0[c * 16 + lr];
        #pragma unroll
        for (int r = 0; r < 4; ++r)
            Ls[(crow0 + r) * STR + c * 16 + lr] = f2bf(fmaxf(acc[r] + bv, 0.f));
    }
    __syncthreads();
    bf16x8 am[4];
    #pragma unroll
    for (int kb = 0; kb < 4; ++kb) am[kb] = *(const bf16x8*)&Ls[afrow * STR + kb * 32 + lk * 8];
    f32x4 tmu[4];
    #pragma unroll
    for (int c = 0; c < 4; ++c) {
        f32x4 acc = {0.f, 0.f, 0.f, 0.f};
        #pragma unroll
        for (int kb = 0; kb < 4; ++kb)
            acc = __builtin_amdgcn_mfma_f32_16x16x32_bf16(am[kb], Pmu[((size_t)c * 4 + kb) * 64 + l], acc, 0, 0, 0);
        tmu[c] = acc;
    }
    __syncthreads();
    #pragma unroll
    for (int c = 0; c < 8; ++c) {
        f32x4 acc = {0.f, 0.f, 0.f, 0.f};
        #pragma unroll
        for (int kb = 0; kb < 4; ++kb)
            acc = __builtin_amdgcn_mfma_f32_16x16x32_bf16(aph[kb], Psi0[((size_t)c * 4 + kb) * 64 + l], acc, 0, 0, 0);
        float bv = b_si0[c * 16 + lr];
        #pragma unroll
        for (int r = 0; r < 4; ++r)
            Ls[(crow0 + r) * STR + c * 16 + lr] = f2bf(fmaxf(acc[r] + bv, 0.f));
    }
    __syncthreads();
    #pragma unroll
    for (int kb = 0; kb < 4; ++kb) am[kb] = *(const bf16x8*)&Ls[afrow * STR + kb * 32 + lk * 8];
    f32x4 tsi[4];
    #pragma unroll
    for (int c = 0; c < 4; ++c) {
        f32x4 acc = {0.f, 0.f, 0.f, 0.f};
        #pragma unroll
        for (int kb = 0; kb < 4; ++kb)
            acc = __builtin_amdgcn_mfma_f32_16x16x32_bf16(am[kb], Psi[((size_t)c * 4 + kb) * 64 + l], acc, 0, 0, 0);
        tsi[c] = acc;
    }
    __syncthreads();
    #pragma unroll
    for (int c = 0; c < 4; ++c) {
        #pragma unroll
        for (int r = 0; r < 4; ++r) {
            Ls[(crow0 + r) * STR + c * 16 + lr]      = f2bf(tmu[c][r]);
            Ls[(crow0 + r) * STR + 64 + c * 16 + lr] = f2bf(tsi[c][r]);
        }
    }
    __syncthreads();
    for (int idx = threadIdx.x; idx < 64 * 16; idx += 256) {
        int row = idx >> 4, c8 = idx & 15;
        if (rowbase + row < N) {
            bf16x8 vv = *(const bf16x8*)&Ls[row * STR + c8 * 8];
            *(bf16x8*)(T + (size_t)(rowbase + row) * 128 + c8 * 8) = vv;
        }
    }
}

// ------------------------------------------------------------------ MFMA GEMM
template <int KI, int KO, int EPI, int OUT>
__global__ __launch_bounds__(256) void mgemm_kernel(const ushort* __restrict__ Xb,
                                                    const bf16x8* __restrict__ Wp,
                                                    const float* __restrict__ bias,
                                                    const float* __restrict__ bias2,
                                                    const float* __restrict__ cvec,
                                                    void* __restrict__ outp, int ostride, int N) {
    constexpr int KB = KI / 32;
    constexpr int CT = KO / 16;
    constexpr size_t LSB = (OUT == 1) ? (size_t)64 * KO * 4 : (size_t)64 * KO * 2;
    __shared__ __align__(16) char LsRaw[LSB];

    int w = threadIdx.x >> 6, l = threadIdx.x & 63;
    int lr = l & 15, lk = l >> 4;
    int rowbase = blockIdx.x * 64;
    int r0 = rowbase + w * 16;

    int arow = r0 + lr; if (arow > N - 1) arow = N - 1;
    bf16x8 a[KB];
    const ushort* xp = Xb + (size_t)arow * KI + lk * 8;
    #pragma unroll
    for (int kb = 0; kb < KB; ++kb) a[kb] = *(const bf16x8*)(xp + kb * 32);

    float cv[4];
    if constexpr (EPI == 3) {
        #pragma unroll
        for (int r = 0; r < 4; ++r) {
            int rr = r0 + lk * 4 + r;
            cv[r] = cvec[rr < N ? rr : 0];
        }
    }

    #pragma unroll
    for (int c = 0; c < CT; ++c) {
        f32x4 acc = {0.f, 0.f, 0.f, 0.f};
        #pragma unroll
        for (int kb = 0; kb < KB; ++kb)
            acc = __builtin_amdgcn_mfma_f32_16x16x32_bf16(a[kb], Wp[((size_t)c * KB + kb) * 64 + l], acc, 0, 0, 0);
        int col = c * 16 + lr;
        float bv = 0.f, b2v = 0.f;
        if constexpr (EPI >= 1) bv = bias[col];
        if constexpr (EPI == 3) b2v = bias2[col];
        #pragma unroll
        for (int r = 0; r < 4; ++r) {
            float v = acc[r];
            if constexpr (EPI == 1) v += bv;
            if constexpr (EPI == 2) v = fmaxf(v + bv, 0.f);
            if constexpr (EPI == 3) v = fmaxf(v + cv[r] * bv + b2v, 0.f);
            int rl = w * 16 + lk * 4 + r;
            if constexpr (OUT == 0) ((ushort*)LsRaw)[(size_t)rl * KO + col] = f2bf(v);
            else                    ((float*)LsRaw)[(size_t)rl * KO + col] = v;
        }
    }
    __syncthreads();

    if constexpr (OUT == 0) {
        ushort* o = (ushort*)outp;
        constexpr int CH = 64 * KO / 8;
        for (int idx = threadIdx.x; idx < CH; idx += 256) {
            int row = idx / (KO / 8), c8 = idx % (KO / 8);
            if (rowbase + row < N)
                *(bf16x8*)(o + (size_t)(rowbase + row) * ostride + c8 * 8) = ((const bf16x8*)LsRaw)[idx];
        }
    } else {
        float* o = (float*)outp;
        constexpr int CH = 64 * KO / 4;
        for (int idx = threadIdx.x; idx < CH; idx += 256) {
            int row = idx / (KO / 4), c4 = idx % (KO / 4);
            if (rowbase + row < N)
                *(float4*)(o + (size_t)(rowbase + row) * ostride + c4 * 4) = ((const float4*)LsRaw)[idx];
        }
    }
}

// ------------------------------------------------------------------ launch
extern "C" void kernel_launch(void* const* d_in, const int* in_sizes, int n_in,
                              void* d_out, int out_size, void* d_ws, size_t ws_size,
                              hipStream_t stream) {
    const float* x    = (const float*)d_in[0];
    const float* eps  = (const float*)d_in[1];
    const int*   ei   = (const int*)d_in[2];
    const float* w_in  = (const float*)d_in[3];  const float* b_in  = (const float*)d_in[4];
    const float* w_mu0 = (const float*)d_in[5];  const float* b_mu0 = (const float*)d_in[6];
    const float* w_mu  = (const float*)d_in[7];  const float* b_mu  = (const float*)d_in[8];
    const float* w_si0 = (const float*)d_in[9];  const float* b_si0 = (const float*)d_in[10];
    const float* w_si  = (const float*)d_in[11]; const float* b_si  = (const float*)d_in[12];
    const float* w_z   = (const float*)d_in[13]; const float* b_z   = (const float*)d_in[14];
    const float* w_d0  = (const float*)d_in[15]; const float* b_d0  = (const float*)d_in[16];
    const float* w_out = (const float*)d_in[17]; const float* b_out = (const float*)d_in[18];

    const int N = in_sizes[0] / 64;
    const int E = in_sizes[2] / 2;
    const int* srcI = ei;
    const int* dstI = ei + E;

    int shift = 4;
    while (((N >> shift) + 1) > 8192) shift++;
    const int NB = (N >> shift) + 1;

    auto align = [](size_t v) { return (v + 255) & ~(size_t)255; };
    char* wsp = (char*)d_ws;
    size_t off = 0;
    int*    deg       = (int*)(wsp + off);    size_t deg_off = off; off = align(off + (size_t)N * 4);
    int*    bc0       = (int*)(wsp + off);    off = align(off + (size_t)NB * 4);
    int*    bc1       = (int*)(wsp + off);    off = align(off + (size_t)NB * 4);
    size_t  zero_span = off - deg_off;
    float*  cvec      = (float*)(wsp + off);  off = align(off + (size_t)N * 4);
    int*    row_start = (int*)(wsp + off);    off = align(off + (size_t)(N + 1) * 4);
    int*    bin_start = (int*)(wsp + off);    off = align(off + (size_t)(NB + 1) * 4);
    int*    bsum      = (int*)(wsp + off);    off = align(off + 1024 * 4);
    float*  dinv      = (float*)(wsp + off);  off = align(off + (size_t)N * 4);
    float*  bzw       = (float*)(wsp + off);  off = align(off + 128 * 4);
    ushort* P_in      = (ushort*)(wsp + off); off = align(off + 64 * 128 * 2);
    ushort* P_mu0     = (ushort*)(wsp + off); off = align(off + 128 * 128 * 2);
    ushort* P_si0     = (ushort*)(wsp + off); off = align(off + 128 * 128 * 2);
    ushort* P_mu      = (ushort*)(wsp + off); off = align(off + 128 * 64 * 2);
    ushort* P_si      = (ushort*)(wsp + off); off = align(off + 128 * 64 * 2);
    ushort* P_wc      = (ushort*)(wsp + off); off = align(off + 64 * 128 * 2);
    ushort* P_out     = (ushort*)(wsp + off); off = align(off + 128 * 128 * 2);
    int2*   csr       = (int2*)(wsp + off);   off = align(off + (size_t)E * 8);
    int2*   ebuf      = (int2*)(wsp + off);   off = align(off + (size_t)E * 8);  // alias: xb after place2
    ushort* xb        = (ushort*)ebuf;        // [N,64] bf16 x, later ppz
    ushort* B1        = (ushort*)(wsp + off); off = align(off + (size_t)N * 128 * 2);
    ushort* B1lo = B1;                        // [N,64]
    ushort* B1hi = B1 + (size_t)N * 64;       // [N,64]

    float* Cc = (float*)d_out;               // logits f32 [N,128] (final)
    float* M  = Cc + (size_t)N * 128;        // mu f32 (final)
    float* S  = M + (size_t)N * 64;          // si f32 (final)
    ushort* CcLo = (ushort*)Cc;              // bf16 [N,128] scratch: h, later r2
    ushort* CcHi = (ushort*)(Cc + (size_t)N * 64);  // bf16 [N,128] scratch: T=[tmu|tsi]
    ushort* Db   = (ushort*)M;               // bf16 [N,128] scratch: ph (dead before pmssz writes M)

    const int TB = 256;
    hipMemsetAsync(deg, 0, zero_span, stream);
    counts_kernel<<<256, 1024, 0, stream>>>(dstI, deg, bc0, E, NB, shift);
    dinv_kernel<<<(N + TB - 1) / TB, TB, 0, stream>>>(deg, dinv, N);
    int nbN = (N + 1023) / 1024;
    scan_block_kernel<<<nbN, 1024, 0, stream>>>(deg, row_start, bsum, N);
    scan_partials_kernel<<<1, 1024, 0, stream>>>(bsum, nbN);
    scan_add_kernel<<<nbN, 1024, 0, stream>>>(row_start, bsum, N, E);
    int nbB = (NB + 1023) / 1024;
    scan_block_kernel<<<nbB, 1024, 0, stream>>>(bc0, bin_start, bsum, NB);
    scan_partials_kernel<<<1, 1024, 0, stream>>>(bsum, nbB);
    scan_add_kernel<<<nbB, 1024, 0, stream>>>(bin_start, bsum, NB, E);
    hipMemsetAsync(deg, 0, (size_t)N * 4, stream);   // deg reused as place counter
    scatter_kernel<<<(E + TB - 1) / TB, TB, 0, stream>>>(srcI, dstI, bin_start, bc1, ebuf, E, shift);
    place2_kernel<<<(E + TB - 1) / TB, TB, 0, stream>>>(ebuf, row_start, deg, csr, dinv, E);
    rowsum_kernel<<<(N + TB - 1) / TB, TB, 0, stream>>>(csr, row_start, dinv, cvec, N);
    wcpack_kernel<<<(65 * 128 + 255) / 256, 256, 0, stream>>>(w_z, b_z, w_d0, P_wc, bzw);
    megapack_kernel<<<288, 256, 0, stream>>>(w_in, w_mu0, w_si0, w_mu, w_si, w_out,
                                             P_in, P_mu0, P_si0, P_mu, P_si, P_out);
    cvt8_kernel<<<((N * 8) + 255) / 256, 256, 0, stream>>>(x, xb, N * 8);  // ebuf alias dead

    int PG = (N + 7) / 8;       // pipelined props: 4 waves x 2 nodes per block
    int GB = (N + 63) / 64;

    // 1. px = P(x) -> B1lo [64]
    pprop_kernel<64><<<PG, 256, 0, stream>>>(xb, B1lo, row_start, csr, dinv, N);
    // 2. h = relu(px@w_in + b) -> CcLo [128]
    mgemm_kernel<64, 128, 2, 0><<<GB, 256, 0, stream>>>(B1lo, (const bf16x8*)P_in, b_in, nullptr, nullptr, CcLo, 128, N);
    // 3. ph = P(h) -> Db [128]
    pprop_kernel<128><<<PG, 256, 0, stream>>>(CcLo, Db, row_start, csr, dinv, N);
    // 4. fused encoder GEMMs: ph -> T=[tmu|tsi] (CcHi); mu1/si1 never leave LDS
    encgemm_kernel<<<GB, 256, 0, stream>>>(Db,
                                           (const bf16x8*)P_mu0, b_mu0, (const bf16x8*)P_mu,
                                           (const bf16x8*)P_si0, b_si0, (const bf16x8*)P_si,
                                           CcHi, N);
    // 5. pmssz: prop T -> mu (M f32), si (S f32), z -> B1lo bf16 (ph dead)
    pmssz_kernel<<<PG, 256, 0, stream>>>(CcHi, row_start, csr, dinv, b_mu, b_si, eps, M, S, B1lo, N);
    // 6. pz = P(z) -> B1hi [64]
    pprop_kernel<64><<<PG, 256, 0, stream>>>(B1lo, B1hi, row_start, csr, dinv, N);
    // 7. ppz = P(pz) -> xb region (x dead)
    pprop_kernel<64><<<PG, 256, 0, stream>>>(B1hi, xb, row_start, csr, dinv, N);
    // 8. r2 = relu(ppz@Wc + cvec*bzw + b_d0) -> CcLo [128] (h dead)
    mgemm_kernel<64, 128, 3, 0><<<GB, 256, 0, stream>>>(xb, (const bf16x8*)P_wc, bzw, b_d0, cvec, CcLo, 128, N);
    // 9. pr2 = P(r2) -> B1 [128] (z/pz dead)
    pprop_kernel<128><<<PG, 256, 0, stream>>>(CcLo, B1, row_start, csr, dinv, N);
    // 10. logits = pr2@w_out + b_out -> Cc f32 (final; reads B1 only)
    mgemm_kernel<128, 128, 1, 1><<<GB, 256, 0, stream>>>(B1, (const bf16x8*)P_out, b_out, nullptr, nullptr, Cc, 128, N);
}